// Round 1
// baseline (4268.903 us; speedup 1.0000x reference)
//
#include <hip/hip_runtime.h>
#include <float.h>

// Problem constants
#define B   32
#define TE  1024
#define TD  64
#define DE  512
#define DD  512
#define U   512
#define K   512   // == DE == DD

#if __has_builtin(__builtin_amdgcn_exp2f)
#define EXP2F __builtin_amdgcn_exp2f
#else
#define EXP2F exp2f
#endif
#if __has_builtin(__builtin_amdgcn_rcpf)
#define RCPF __builtin_amdgcn_rcpf
#else
#define RCPF(x) (1.0f / (x))
#endif

__device__ __forceinline__ float tanh_fast(float x) {
    // tanh(x) = 1 - 2/(e^{2x}+1); e^{2x} = 2^{x * 2*log2(e)}
    float e = EXP2F(x * 2.8853900817779268f);
    return 1.0f - 2.0f * RCPF(e + 1.0f);   // inf -> 1, 0 -> -1 : correct saturation
}

__device__ __forceinline__ float wave_reduce_sum(float v) {
    #pragma unroll
    for (int o = 32; o; o >>= 1) v += __shfl_xor(v, o, 64);
    return v;
}
__device__ __forceinline__ float wave_reduce_max(float v) {
    #pragma unroll
    for (int o = 32; o; o >>= 1) v = fmaxf(v, __shfl_xor(v, o, 64));
    return v;
}

// ---------------------------------------------------------------------------
// zero coverage: 32768 floats, 32 blocks x 256 threads x float4
__global__ void k_zero(float4* __restrict__ p) {
    p[blockIdx.x * 256 + threadIdx.x] = make_float4(0.f, 0.f, 0.f, 0.f);
}

// ---------------------------------------------------------------------------
// C[M,512] = (A * maybe_mask) @ W[512,512].  64x64 tile, BK=16, 256 thr, 4x4/thr
__global__ __launch_bounds__(256) void k_gemm(const float* __restrict__ A,
                                              const float* __restrict__ W,
                                              float* __restrict__ C,
                                              const int* __restrict__ mask) {
    __shared__ __align__(16) float As[16][68];  // [k][m], padded (68%4==0 keeps 16B align)
    __shared__ __align__(16) float Bs[16][64];  // [k][n]
    const int tid = threadIdx.x;
    const int tx = tid & 15;        // n-group
    const int ty = tid >> 4;        // m-group
    const int m0 = blockIdx.y * 64;
    const int n0 = blockIdx.x * 64;

    float acc[4][4];
    #pragma unroll
    for (int i = 0; i < 4; i++)
        #pragma unroll
        for (int j = 0; j < 4; j++) acc[i][j] = 0.f;

    for (int k0 = 0; k0 < K; k0 += 16) {
        #pragma unroll
        for (int i = 0; i < 4; i++) {          // A tile 64x16
            int id = i * 256 + tid;
            int m = id >> 4, kk = id & 15;
            float val = A[(size_t)(m0 + m) * K + k0 + kk];
            if (mask) val = mask[m0 + m] ? val : 0.f;
            As[kk][m] = val;
        }
        #pragma unroll
        for (int i = 0; i < 4; i++) {          // B tile 16x64
            int id = i * 256 + tid;
            int n = id & 63, kk = id >> 6;
            Bs[kk][n] = W[(size_t)(k0 + kk) * U + n0 + n];
        }
        __syncthreads();
        #pragma unroll
        for (int kk = 0; kk < 16; kk++) {
            float4 a4 = *(const float4*)&As[kk][ty * 4];
            float4 b4 = *(const float4*)&Bs[kk][tx * 4];
            float a[4] = {a4.x, a4.y, a4.z, a4.w};
            float b[4] = {b4.x, b4.y, b4.z, b4.w};
            #pragma unroll
            for (int i = 0; i < 4; i++)
                #pragma unroll
                for (int j = 0; j < 4; j++) acc[i][j] += a[i] * b[j];
        }
        __syncthreads();
    }
    #pragma unroll
    for (int i = 0; i < 4; i++) {
        float4 r = make_float4(acc[i][0], acc[i][1], acc[i][2], acc[i][3]);
        *(float4*)&C[(size_t)(m0 + ty * 4 + i) * U + n0 + tx * 4] = r;
    }
}

// ---------------------------------------------------------------------------
// mu[b,t] = sum_u v[u]*tanh(enc_feat[b,t,u] + dec_feat[b,s,u] + cov[b,t]*w_c[u])
// masked t -> mu = -1e30 sentinel (alpha underflows to exactly 0, matching ref).
// One wave per 16 consecutive t of one b. 512 blocks x 256 thr (2048 waves).
__global__ __launch_bounds__(256) void k_mu(const float* __restrict__ enc_feat,
                                            const float* __restrict__ dec_feat,
                                            const float* __restrict__ w_c,
                                            const float* __restrict__ v,
                                            const float* __restrict__ coverage,
                                            const int* __restrict__ mask,
                                            float* __restrict__ mu, int s) {
    const int gw   = blockIdx.x * 4 + (threadIdx.x >> 6);
    const int lane = threadIdx.x & 63;
    const int b    = gw >> 6;
    const int t0   = (gw & 63) << 4;
    const int u    = lane * 8;

    const float* dfp = dec_feat + ((size_t)b * TD + s) * U + u;
    float4 df1 = *(const float4*)dfp;
    float4 df2 = *(const float4*)(dfp + 4);
    float4 wc1 = *(const float4*)&w_c[u];
    float4 wc2 = *(const float4*)&w_c[u + 4];
    float4 v1  = *(const float4*)&v[u];
    float4 v2  = *(const float4*)&v[u + 4];

    const int*   maskb = mask + b * TE;
    const float* covb  = coverage + b * TE;
    float*       mub   = mu + b * TE;
    const float* encb  = enc_feat + ((size_t)b * TE + t0) * U + u;

    for (int tt = 0; tt < 16; tt++) {
        int t = t0 + tt;
        if (maskb[t] == 0) {                 // wave-uniform branch
            if (lane == 0) mub[t] = -1e30f;
            continue;
        }
        float cov = covb[t];
        const float* ef = encb + (size_t)tt * U;
        float4 e1 = *(const float4*)ef;
        float4 e2 = *(const float4*)(ef + 4);
        float acc;
        acc  = v1.x * tanh_fast(fmaf(cov, wc1.x, e1.x + df1.x));
        acc += v1.y * tanh_fast(fmaf(cov, wc1.y, e1.y + df1.y));
        acc += v1.z * tanh_fast(fmaf(cov, wc1.z, e1.z + df1.z));
        acc += v1.w * tanh_fast(fmaf(cov, wc1.w, e1.w + df1.w));
        acc += v2.x * tanh_fast(fmaf(cov, wc2.x, e2.x + df2.x));
        acc += v2.y * tanh_fast(fmaf(cov, wc2.y, e2.y + df2.y));
        acc += v2.z * tanh_fast(fmaf(cov, wc2.z, e2.z + df2.z));
        acc += v2.w * tanh_fast(fmaf(cov, wc2.w, e2.w + df2.w));
        acc = wave_reduce_sum(acc);
        if (lane == 0) mub[t] = acc;
    }
}

// ---------------------------------------------------------------------------
// Per step: softmax stats (recomputed by all 8 blocks of a batch), ctx
// accumulation over the block's 64-wide e-chunk, and (ec==0) output writes:
// alphas, covloss, coverage update, de_seq passthrough.
// Grid: 256 blocks (b = blk/8, e-chunk = blk%8), 512 threads.
__global__ __launch_bounds__(512) void k_ctx(const float* __restrict__ mu,
                                             const float* __restrict__ en_seq,
                                             const float* __restrict__ de_seq,
                                             float* __restrict__ coverage,
                                             float* __restrict__ out, int s) {
    const int b   = blockIdx.x >> 3;
    const int ec  = blockIdx.x & 7;
    const int tid = threadIdx.x;
    const int lane = tid & 63, wid = tid >> 6;
    __shared__ float s_red[8];
    __shared__ float s_ctx[8][64];

    const float* mub = mu + b * TE;
    const float L2E = 1.4426950408889634f;

    // --- softmax stats over TE (masked entries carry -1e30 sentinel) ---
    float m1 = mub[tid], m2 = mub[tid + 512];
    float wmax = wave_reduce_max(fmaxf(m1, m2));
    if (lane == 0) s_red[wid] = wmax;
    __syncthreads();
    float mx = s_red[0];
    #pragma unroll
    for (int i = 1; i < 8; i++) mx = fmaxf(mx, s_red[i]);
    __syncthreads();
    float e1 = EXP2F((m1 - mx) * L2E);       // masked -> exp2(-huge) == 0
    float e2 = EXP2F((m2 - mx) * L2E);
    float wsum = wave_reduce_sum(e1 + e2);
    if (lane == 0) s_red[wid] = wsum;
    __syncthreads();
    float tot = 0.f;
    #pragma unroll
    for (int i = 0; i < 8; i++) tot += s_red[i];
    float inv = RCPF(tot);

    // --- ctx: this block covers e in [ec*64, ec*64+64), all t ---
    const int e  = ec * 64 + (tid & 63);
    const int tg = tid >> 6;
    float acc = 0.f;
    const float* enb = en_seq + (size_t)b * TE * DE;
    for (int t = tg * 128; t < tg * 128 + 128; t++) {
        float mt = mub[t];
        if (mt == -1e30f) continue;          // wave-uniform: alpha == 0 exactly
        float a = EXP2F((mt - mx) * L2E) * inv;
        acc += a * enb[(size_t)t * DE + e];
    }
    s_ctx[tg][tid & 63] = acc;
    __syncthreads();
    if (tid < 64) {
        float tsum = 0.f;
        #pragma unroll
        for (int g = 0; g < 8; g++) tsum += s_ctx[g][tid];
        out[((size_t)b * TD + s) * (DD + DE) + DD + ec * 64 + tid] = tsum;
    }

    // --- per-step scalar outputs (one block per b) ---
    if (ec == 0) {
        float* alphas = out + (size_t)B * TD * (DD + DE);
        float* covl   = alphas + (size_t)B * TD * TE;
        size_t rowo = ((size_t)b * TD + s) * TE;
        #pragma unroll
        for (int i = 0; i < 2; i++) {
            int t = tid + i * 512;
            float mt = mub[t];
            float a = EXP2F((mt - mx) * L2E) * inv;   // masked -> 0
            float cov = coverage[b * TE + t];
            alphas[rowo + t] = a;
            covl[rowo + t]   = fminf(cov, a);
            coverage[b * TE + t] = cov + a;
        }
        // de_seq passthrough into output[:, :, 0:DD]
        out[((size_t)b * TD + s) * (DD + DE) + tid] =
            de_seq[((size_t)b * TD + s) * DD + tid];
    }
}

// ---------------------------------------------------------------------------
extern "C" void kernel_launch(void* const* d_in, const int* in_sizes, int n_in,
                              void* d_out, int out_size, void* d_ws, size_t ws_size,
                              hipStream_t stream) {
    const float* en_seq = (const float*)d_in[0];
    const float* de_seq = (const float*)d_in[1];
    const int*   mask   = (const int*)d_in[2];
    const float* W_h    = (const float*)d_in[3];
    const float* W_s    = (const float*)d_in[4];
    const float* w_c    = (const float*)d_in[5];
    const float* v      = (const float*)d_in[6];
    float* out = (float*)d_out;
    float* ws  = (float*)d_ws;

    // workspace layout (floats): needs ~68.3 MiB
    float* enc_feat = ws;                               // B*TE*U = 16777216
    float* dec_feat = ws + 16777216;                    // B*TD*U = 1048576
    float* coverage = ws + 16777216 + 1048576;          // B*TE   = 32768
    float* mu       = coverage + 32768;                 // B*TE   = 32768

    k_zero<<<32, 256, 0, stream>>>((float4*)coverage);
    k_gemm<<<dim3(U / 64, (B * TE) / 64), 256, 0, stream>>>(en_seq, W_h, enc_feat, mask);
    k_gemm<<<dim3(U / 64, (B * TD) / 64), 256, 0, stream>>>(de_seq, W_s, dec_feat, nullptr);

    for (int s = 0; s < TD; s++) {
        k_mu<<<512, 256, 0, stream>>>(enc_feat, dec_feat, w_c, v, coverage, mask, mu, s);
        k_ctx<<<256, 512, 0, stream>>>(mu, en_seq, de_seq, coverage, out, s);
    }
}

// Round 2
// 3211.972 us; speedup vs baseline: 1.3291x; 1.3291x over previous
//
#include <hip/hip_runtime.h>
#include <float.h>

// Problem constants
#define B   32
#define TE  1024
#define TD  64
#define DE  512
#define DD  512
#define U   512
#define K   512   // == DE == DD

#if __has_builtin(__builtin_amdgcn_exp2f)
#define EXP2F __builtin_amdgcn_exp2f
#else
#define EXP2F exp2f
#endif
#if __has_builtin(__builtin_amdgcn_rcpf)
#define RCPF __builtin_amdgcn_rcpf
#else
#define RCPF(x) (1.0f / (x))
#endif

#define SENTINEL -1e30f

__device__ __forceinline__ float tanh_fast(float x) {
    float e = EXP2F(x * 2.8853900817779268f);   // e^{2x}
    return 1.0f - 2.0f * RCPF(e + 1.0f);        // saturates correctly at +-inf
}

__device__ __forceinline__ float wave_reduce_sum(float v) {
    #pragma unroll
    for (int o = 32; o; o >>= 1) v += __shfl_xor(v, o, 64);
    return v;
}
__device__ __forceinline__ float wave_reduce_max(float v) {
    #pragma unroll
    for (int o = 32; o; o >>= 1) v = fmaxf(v, __shfl_xor(v, o, 64));
    return v;
}

// f32 -> bf16 RNE
__device__ __forceinline__ unsigned short f2bf(float f) {
    unsigned u = __float_as_uint(f);
    unsigned r = (u + 0x7fffu + ((u >> 16) & 1u)) >> 16;
    return (unsigned short)r;
}
__device__ __forceinline__ float bflo(unsigned x) { return __uint_as_float(x << 16); }
__device__ __forceinline__ float bfhi(unsigned x) { return __uint_as_float(x & 0xffff0000u); }
__device__ __forceinline__ void unpack8(uint4 q, float* f) {
    f[0] = bflo(q.x); f[1] = bfhi(q.x); f[2] = bflo(q.y); f[3] = bfhi(q.y);
    f[4] = bflo(q.z); f[5] = bfhi(q.z); f[6] = bflo(q.w); f[7] = bfhi(q.w);
}
__device__ __forceinline__ float bf2f(unsigned short s) {
    return __uint_as_float(((unsigned)s) << 16);
}

// ---------------------------------------------------------------------------
// init: coverage=0, mu=SENTINEL (masked entries keep it forever), sync cnt=0
__global__ __launch_bounds__(256) void k_init(float* __restrict__ cov,
                                              float* __restrict__ mu,
                                              int* __restrict__ cnt) {
    int i = blockIdx.x * 256 + threadIdx.x;   // grid 128*256 = 32768
    cov[i] = 0.f;
    mu[i]  = SENTINEL;
    if (i < 512) cnt[i] = 0;
}

// en_seq f32 -> bf16 (no mask needed; masked rows are skipped downstream)
__global__ __launch_bounds__(256) void k_cast(const float4* __restrict__ in,
                                              ushort4* __restrict__ outp) {
    size_t i = (size_t)blockIdx.x * 256 + threadIdx.x;
    float4 f = in[i];
    ushort4 r;
    r.x = f2bf(f.x); r.y = f2bf(f.y); r.z = f2bf(f.z); r.w = f2bf(f.w);
    outp[i] = r;
}

// de_seq passthrough into out[:, :, 0:DD] (strided copy, step-independent)
__global__ __launch_bounds__(256) void k_pass(const float4* __restrict__ de,
                                              float4* __restrict__ outp) {
    size_t i = (size_t)blockIdx.x * 256 + threadIdx.x;  // 262144 float4
    size_t r = i >> 7, c = i & 127;                     // 128 float4 per row
    outp[r * 256 + c] = de[i];                          // out row = 256 float4
}

// ---------------------------------------------------------------------------
// C_bf16[M,512] = A[M,512] @ W[512,512].  64x64 tile, BK=16, 256 thr, 4x4/thr
__global__ __launch_bounds__(256) void k_gemm_bf(const float* __restrict__ A,
                                                 const float* __restrict__ W,
                                                 unsigned short* __restrict__ C) {
    __shared__ __align__(16) float As[16][68];
    __shared__ __align__(16) float Bs[16][64];
    const int tid = threadIdx.x;
    const int tx = tid & 15;
    const int ty = tid >> 4;
    const int m0 = blockIdx.y * 64;
    const int n0 = blockIdx.x * 64;

    float acc[4][4];
    #pragma unroll
    for (int i = 0; i < 4; i++)
        #pragma unroll
        for (int j = 0; j < 4; j++) acc[i][j] = 0.f;

    for (int k0 = 0; k0 < K; k0 += 16) {
        #pragma unroll
        for (int i = 0; i < 4; i++) {
            int id = i * 256 + tid;
            int m = id >> 4, kk = id & 15;
            As[kk][m] = A[(size_t)(m0 + m) * K + k0 + kk];
        }
        #pragma unroll
        for (int i = 0; i < 4; i++) {
            int id = i * 256 + tid;
            int n = id & 63, kk = id >> 6;
            Bs[kk][n] = W[(size_t)(k0 + kk) * U + n0 + n];
        }
        __syncthreads();
        #pragma unroll
        for (int kk = 0; kk < 16; kk++) {
            float4 a4 = *(const float4*)&As[kk][ty * 4];
            float4 b4 = *(const float4*)&Bs[kk][tx * 4];
            float a[4] = {a4.x, a4.y, a4.z, a4.w};
            float b[4] = {b4.x, b4.y, b4.z, b4.w};
            #pragma unroll
            for (int i = 0; i < 4; i++)
                #pragma unroll
                for (int j = 0; j < 4; j++) acc[i][j] += a[i] * b[j];
        }
        __syncthreads();
    }
    #pragma unroll
    for (int i = 0; i < 4; i++) {
        ushort4 r;
        r.x = f2bf(acc[i][0]); r.y = f2bf(acc[i][1]);
        r.z = f2bf(acc[i][2]); r.w = f2bf(acc[i][3]);
        *(ushort4*)&C[(size_t)(m0 + ty * 4 + i) * U + n0 + tx * 4] = r;
    }
}

// ---------------------------------------------------------------------------
// per-batch sync among the 8 blocks of batch b. Monotone counter, never reset.
__device__ __forceinline__ void batch_sync(int* c, int target) {
    __syncthreads();
    if (threadIdx.x == 0) {
        __hip_atomic_fetch_add(c, 1, __ATOMIC_RELEASE, __HIP_MEMORY_SCOPE_AGENT);
        while (__hip_atomic_load(c, __ATOMIC_ACQUIRE, __HIP_MEMORY_SCOPE_AGENT) < target)
            __builtin_amdgcn_s_sleep(1);
    }
    __syncthreads();
}

// ---------------------------------------------------------------------------
// Persistent scan: 256 blocks x 1024 threads, cooperative launch.
// block -> (b = blk>>3, g = blk&7). Per step:
//   Phase A: mu for t in [g*128,(g+1)*128), one wave per row, masked skipped.
//   sync; Phase B: redundant softmax stats -> s_alpha in LDS; ctx for e-chunk
//   [g*64,g*64+64); g==0 writes alphas/covloss/coverage; sync.
__global__ __launch_bounds__(1024) void k_scan(
        const unsigned short* __restrict__ enc_bf,
        const unsigned short* __restrict__ dec_bf,
        const unsigned short* __restrict__ en_bf,
        const float* __restrict__ w_c,
        const float* __restrict__ v,
        const int* __restrict__ mask,
        float* __restrict__ coverage,
        float* __restrict__ mu,
        int* __restrict__ cnt,
        float* __restrict__ out)
{
    const int blk = blockIdx.x;
    const int b = blk >> 3, g = blk & 7;
    const int tid = threadIdx.x;
    const int w = tid >> 6, lane = tid & 63;
    const int u = lane * 8;
    const float L2E = 1.4426950408889634f;

    __shared__ float s_red[16];
    __shared__ float s_alpha[TE];
    __shared__ float s_ctx[16][64];

    float wc[8], vv[8];
    {
        float4 a = *(const float4*)&w_c[u];
        float4 c = *(const float4*)&w_c[u + 4];
        wc[0] = a.x; wc[1] = a.y; wc[2] = a.z; wc[3] = a.w;
        wc[4] = c.x; wc[5] = c.y; wc[6] = c.z; wc[7] = c.w;
        float4 d = *(const float4*)&v[u];
        float4 e = *(const float4*)&v[u + 4];
        vv[0] = d.x; vv[1] = d.y; vv[2] = d.z; vv[3] = d.w;
        vv[4] = e.x; vv[5] = e.y; vv[6] = e.z; vv[7] = e.w;
    }

    const int*   maskb = mask + b * TE;
    float*       covb  = coverage + (size_t)b * TE;
    float*       mub   = mu + (size_t)b * TE;
    const unsigned short* encb = enc_bf + (size_t)b * TE * U;
    const unsigned short* enb  = en_bf  + (size_t)b * TE * DE;
    int* cbp = cnt + b * 16;

    float* alphas = out + (size_t)B * TD * (DD + DE);
    float* covl   = alphas + (size_t)B * TD * TE;

    for (int s = 0; s < TD; s++) {
        // ---- df for this (b,s): 8 bf16 per lane -> registers
        float df[8];
        {
            uint4 q = *(const uint4*)(dec_bf + (((size_t)b * TD + s) * U + u));
            unpack8(q, df);
        }

        // ---- Phase A: mu
        #pragma unroll
        for (int i = 0; i < 8; i++) {
            int t = g * 128 + w + i * 16;
            if (maskb[t] == 0) continue;          // wave-uniform
            float cov = covb[t];
            uint4 q = *(const uint4*)(encb + ((size_t)t * U + u));
            float e[8]; unpack8(q, e);
            float acc = 0.f;
            #pragma unroll
            for (int j = 0; j < 8; j++)
                acc += vv[j] * tanh_fast(fmaf(cov, wc[j], e[j] + df[j]));
            acc = wave_reduce_sum(acc);
            if (lane == 0) mub[t] = acc;
        }

        batch_sync(cbp, 8 * (2 * s + 1));

        // ---- Phase B: softmax stats (redundant per block)
        float m1 = mub[tid];
        float wmax = wave_reduce_max(m1);
        if (lane == 0) s_red[w] = wmax;
        __syncthreads();
        float mx = s_red[0];
        #pragma unroll
        for (int i = 1; i < 16; i++) mx = fmaxf(mx, s_red[i]);
        __syncthreads();
        float e1 = EXP2F((m1 - mx) * L2E);        // masked -> exactly 0
        float wsum = wave_reduce_sum(e1);
        if (lane == 0) s_red[w] = wsum;
        __syncthreads();
        float tot = 0.f;
        #pragma unroll
        for (int i = 0; i < 16; i++) tot += s_red[i];
        float inv = RCPF(tot);
        s_alpha[tid] = e1 * inv;
        __syncthreads();

        // ---- ctx: e-chunk [g*64, g*64+64), wave w covers t in [w*64,(w+1)*64)
        {
            const int e0 = g * 64 + lane;
            float acc = 0.f;
            for (int t = w * 64; t < w * 64 + 64; t++) {
                float a = s_alpha[t];
                if (a == 0.f) continue;           // wave-uniform: masked row
                acc = fmaf(a, bf2f(enb[(size_t)t * DE + e0]), acc);
            }
            s_ctx[w][lane] = acc;
        }

        // ---- group 0: alphas / covloss / coverage update
        if (g == 0) {
            float a = s_alpha[tid];
            float cov = covb[tid];
            size_t rowo = ((size_t)b * TD + s) * TE;
            alphas[rowo + tid] = a;
            covl[rowo + tid]   = fminf(cov, a);
            covb[tid] = cov + a;
        }
        __syncthreads();
        if (tid < 64) {
            float ts = 0.f;
            #pragma unroll
            for (int k = 0; k < 16; k++) ts += s_ctx[k][tid];
            out[((size_t)b * TD + s) * (DD + DE) + DD + g * 64 + tid] = ts;
        }

        batch_sync(cbp, 8 * (2 * s + 2));
    }
}

// ---------------------------------------------------------------------------
extern "C" void kernel_launch(void* const* d_in, const int* in_sizes, int n_in,
                              void* d_out, int out_size, void* d_ws, size_t ws_size,
                              hipStream_t stream) {
    const float* en_seq = (const float*)d_in[0];
    const float* de_seq = (const float*)d_in[1];
    const int*   mask   = (const int*)d_in[2];
    const float* W_h    = (const float*)d_in[3];
    const float* W_s    = (const float*)d_in[4];
    const float* w_c    = (const float*)d_in[5];
    const float* v      = (const float*)d_in[6];
    float* out = (float*)d_out;

    // workspace layout (~66.3 MiB)
    unsigned short* enc_bf = (unsigned short*)d_ws;       // B*TE*U  bf16
    unsigned short* en_bf  = enc_bf + (size_t)B * TE * U; // B*TE*DE bf16
    unsigned short* dec_bf = en_bf  + (size_t)B * TE * DE;// B*TD*U  bf16
    float* coverage = (float*)(dec_bf + (size_t)B * TD * U);
    float* mu       = coverage + B * TE;
    int*   cnt      = (int*)(mu + B * TE);                // 32 batches * 16 ints

    k_init<<<128, 256, 0, stream>>>(coverage, mu, cnt);
    k_cast<<<16384, 256, 0, stream>>>((const float4*)en_seq, (ushort4*)en_bf);
    k_pass<<<1024, 256, 0, stream>>>((const float4*)de_seq, (float4*)out);
    k_gemm_bf<<<dim3(U / 64, (B * TE) / 64), 256, 0, stream>>>(en_seq, W_h, enc_bf);
    k_gemm_bf<<<dim3(U / 64, (B * TD) / 64), 256, 0, stream>>>(de_seq, W_s, dec_bf);

    void* args[] = { (void*)&enc_bf, (void*)&dec_bf, (void*)&en_bf,
                     (void*)&w_c, (void*)&v, (void*)&mask,
                     (void*)&coverage, (void*)&mu, (void*)&cnt, (void*)&out };
    hipLaunchCooperativeKernel((const void*)k_scan, dim3(256), dim3(1024),
                               args, 0, stream);
}

// Round 3
// 2247.602 us; speedup vs baseline: 1.8993x; 1.4291x over previous
//
#include <hip/hip_runtime.h>
#include <float.h>

// Problem constants
#define B   32
#define TE  1024
#define TD  64
#define DE  512
#define DD  512
#define U   512
#define K   512   // == DE == DD

#if __has_builtin(__builtin_amdgcn_exp2f)
#define EXP2F __builtin_amdgcn_exp2f
#else
#define EXP2F exp2f
#endif
#if __has_builtin(__builtin_amdgcn_rcpf)
#define RCPF __builtin_amdgcn_rcpf
#else
#define RCPF(x) (1.0f / (x))
#endif

#define SENTINEL -1e30f

__device__ __forceinline__ float tanh_fast(float x) {
    float e = EXP2F(x * 2.8853900817779268f);   // e^{2x}
    return 1.0f - 2.0f * RCPF(e + 1.0f);        // saturates correctly at +-inf
}

__device__ __forceinline__ float wave_reduce_sum(float v) {
    #pragma unroll
    for (int o = 32; o; o >>= 1) v += __shfl_xor(v, o, 64);
    return v;
}
__device__ __forceinline__ float wave_reduce_max(float v) {
    #pragma unroll
    for (int o = 32; o; o >>= 1) v = fmaxf(v, __shfl_xor(v, o, 64));
    return v;
}

// f32 -> bf16 RNE
__device__ __forceinline__ unsigned short f2bf(float f) {
    unsigned u = __float_as_uint(f);
    unsigned r = (u + 0x7fffu + ((u >> 16) & 1u)) >> 16;
    return (unsigned short)r;
}
__device__ __forceinline__ float bflo(unsigned x) { return __uint_as_float(x << 16); }
__device__ __forceinline__ float bfhi(unsigned x) { return __uint_as_float(x & 0xffff0000u); }
__device__ __forceinline__ void unpack8(uint4 q, float* f) {
    f[0] = bflo(q.x); f[1] = bfhi(q.x); f[2] = bflo(q.y); f[3] = bfhi(q.y);
    f[4] = bflo(q.z); f[5] = bfhi(q.z); f[6] = bflo(q.w); f[7] = bfhi(q.w);
}

// ---------------------------------------------------------------------------
// init: mu=SENTINEL (masked entries keep it forever), sync cnt=0
__global__ __launch_bounds__(256) void k_init(float* __restrict__ mu,
                                              int* __restrict__ cnt) {
    int i = blockIdx.x * 256 + threadIdx.x;   // grid 128*256 = 32768
    mu[i] = SENTINEL;
    if (i < 512) cnt[i] = 0;
}

// en_seq f32 -> bf16
__global__ __launch_bounds__(256) void k_cast(const float4* __restrict__ in,
                                              ushort4* __restrict__ outp) {
    size_t i = (size_t)blockIdx.x * 256 + threadIdx.x;
    float4 f = in[i];
    ushort4 r;
    r.x = f2bf(f.x); r.y = f2bf(f.y); r.z = f2bf(f.z); r.w = f2bf(f.w);
    outp[i] = r;
}

// de_seq passthrough into out[:, :, 0:DD]
__global__ __launch_bounds__(256) void k_pass(const float4* __restrict__ de,
                                              float4* __restrict__ outp) {
    size_t i = (size_t)blockIdx.x * 256 + threadIdx.x;  // 262144 float4
    size_t r = i >> 7, c = i & 127;
    outp[r * 256 + c] = de[i];
}

// ---------------------------------------------------------------------------
// C_bf16[M,512] = A[M,512] @ W[512,512].  64x64 tile, BK=16, 256 thr, 4x4/thr
__global__ __launch_bounds__(256) void k_gemm_bf(const float* __restrict__ A,
                                                 const float* __restrict__ W,
                                                 unsigned short* __restrict__ C) {
    __shared__ __align__(16) float As[16][68];
    __shared__ __align__(16) float Bs[16][64];
    const int tid = threadIdx.x;
    const int tx = tid & 15;
    const int ty = tid >> 4;
    const int m0 = blockIdx.y * 64;
    const int n0 = blockIdx.x * 64;

    float acc[4][4];
    #pragma unroll
    for (int i = 0; i < 4; i++)
        #pragma unroll
        for (int j = 0; j < 4; j++) acc[i][j] = 0.f;

    for (int k0 = 0; k0 < K; k0 += 16) {
        #pragma unroll
        for (int i = 0; i < 4; i++) {
            int id = i * 256 + tid;
            int m = id >> 4, kk = id & 15;
            As[kk][m] = A[(size_t)(m0 + m) * K + k0 + kk];
        }
        #pragma unroll
        for (int i = 0; i < 4; i++) {
            int id = i * 256 + tid;
            int n = id & 63, kk = id >> 6;
            Bs[kk][n] = W[(size_t)(k0 + kk) * U + n0 + n];
        }
        __syncthreads();
        #pragma unroll
        for (int kk = 0; kk < 16; kk++) {
            float4 a4 = *(const float4*)&As[kk][ty * 4];
            float4 b4 = *(const float4*)&Bs[kk][tx * 4];
            float a[4] = {a4.x, a4.y, a4.z, a4.w};
            float b[4] = {b4.x, b4.y, b4.z, b4.w};
            #pragma unroll
            for (int i = 0; i < 4; i++)
                #pragma unroll
                for (int j = 0; j < 4; j++) acc[i][j] += a[i] * b[j];
        }
        __syncthreads();
    }
    #pragma unroll
    for (int i = 0; i < 4; i++) {
        ushort4 r;
        r.x = f2bf(acc[i][0]); r.y = f2bf(acc[i][1]);
        r.z = f2bf(acc[i][2]); r.w = f2bf(acc[i][3]);
        *(ushort4*)&C[(size_t)(m0 + ty * 4 + i) * U + n0 + tx * 4] = r;
    }
}

// ---------------------------------------------------------------------------
// per-batch sync among the 8 blocks of batch b. Monotone counter, never reset.
__device__ __forceinline__ void batch_sync(int* c, int target) {
    __syncthreads();
    if (threadIdx.x == 0) {
        __hip_atomic_fetch_add(c, 1, __ATOMIC_RELEASE, __HIP_MEMORY_SCOPE_AGENT);
        while (__hip_atomic_load(c, __ATOMIC_ACQUIRE, __HIP_MEMORY_SCOPE_AGENT) < target)
            __builtin_amdgcn_s_sleep(1);
    }
    __syncthreads();
}

// ---------------------------------------------------------------------------
// Persistent scan: 256 blocks x 1024 threads, cooperative.
// block -> (b = blk>>3, g = blk&7); owns t-rows [g*128, g*128+128).
//   enc slice for own rows lives in LDS (128 KB, loaded once).
//   Per step: [deferred ctx-reduce of s-1] -> mu(own rows) -> sync1 ->
//   softmax (redundant, from global mu) -> own-row cov/alphas/covloss ->
//   partial ctx over own rows x all 512 e -> pctx[parity] -> sync2.
// Final ctx reduce for s=TD-1 after the loop.
__global__ __launch_bounds__(1024, 4) void k_scan(
        const unsigned short* __restrict__ enc_bf,
        const unsigned short* __restrict__ dec_bf,
        const unsigned short* __restrict__ en_bf,
        const float* __restrict__ w_c,
        const float* __restrict__ v,
        const int* __restrict__ mask,
        float* __restrict__ mu,
        float* __restrict__ pctx,     // [2][B][8][512] f32
        int* __restrict__ cnt,
        float* __restrict__ out)
{
    const int blk = blockIdx.x;
    const int b = blk >> 3, g = blk & 7;
    const int tid = threadIdx.x;
    const int w = tid >> 6, lane = tid & 63;
    const int u = lane * 8;
    const float L2E = 1.4426950408889634f;

    __shared__ __align__(16) unsigned short s_enc[128 * U];  // 128 KiB
    __shared__ float  s_alpha[TE];                           // 4 KiB
    __shared__ float2 s_pctx[4][256];                        // 8 KiB
    __shared__ float  s_red[16];
    __shared__ float  s_cov[128];
    __shared__ int    s_active[128];
    __shared__ int    s_cnt[2];
    __shared__ int    s_nact;

    const int*   maskb = mask + b * TE;
    float*       mub   = mu + (size_t)b * TE;
    const unsigned short* encb = enc_bf + ((size_t)b * TE + g * 128) * U;
    const unsigned short* enb  = en_bf  + (size_t)b * TE * DE;
    int* cbp = cnt + b * 16;
    float* alphas = out + (size_t)B * TD * (DD + DE);
    float* covl   = alphas + (size_t)B * TD * TE;

    // lane-resident w_c / v fragments
    float wc[8], vv[8];
    {
        float4 a0 = *(const float4*)&w_c[u];
        float4 a1 = *(const float4*)&w_c[u + 4];
        wc[0]=a0.x; wc[1]=a0.y; wc[2]=a0.z; wc[3]=a0.w;
        wc[4]=a1.x; wc[5]=a1.y; wc[6]=a1.z; wc[7]=a1.w;
        float4 b0 = *(const float4*)&v[u];
        float4 b1 = *(const float4*)&v[u + 4];
        vv[0]=b0.x; vv[1]=b0.y; vv[2]=b0.z; vv[3]=b0.w;
        vv[4]=b1.x; vv[5]=b1.y; vv[6]=b1.z; vv[7]=b1.w;
    }

    // stage own enc slice into LDS: 131072 B = 8192 uint4, 8 iters
    {
        const uint4* src = (const uint4*)encb;
        uint4* dst = (uint4*)s_enc;
        #pragma unroll
        for (int i = 0; i < 8; i++) dst[i * 1024 + tid] = src[i * 1024 + tid];
    }

    // active-row compaction (ballot) + coverage init
    {
        int act = 0;
        if (tid < 128) act = (maskb[g * 128 + tid] != 0);
        unsigned long long bal = __ballot(act);
        int pre = __popcll(bal & ((1ull << lane) - 1));
        if (w < 2 && lane == 0) s_cnt[w] = __popcll(bal);
        if (tid < 128) s_cov[tid] = 0.f;
        __syncthreads();
        if (act) {
            int base = (w == 1) ? s_cnt[0] : 0;
            s_active[base + pre] = tid;       // t_local
        }
        if (tid == 0) s_nact = s_cnt[0] + s_cnt[1];
        __syncthreads();
    }
    const int n_act = s_nact;

    for (int s = 0; s < TD; s++) {
        // ---- deferred ctx reduce for step s-1 (pctx published by last sync2)
        if (s > 0 && w == 0) {
            const float* pp = pctx + ((size_t)((s - 1) & 1) * B * 8 + (size_t)b * 8) * 512;
            float ts = 0.f;
            #pragma unroll
            for (int gg = 0; gg < 8; gg++) ts += pp[gg * 512 + g * 64 + lane];
            out[((size_t)b * TD + (s - 1)) * (DD + DE) + DD + g * 64 + lane] = ts;
        }

        // ---- dec fragment for (b,s)
        float df[8];
        {
            uint4 q = *(const uint4*)(dec_bf + (((size_t)b * TD + s) * U + u));
            unpack8(q, df);
        }

        // ---- Phase A: mu over active own rows (enc from LDS)
        for (int i = w; i < n_act; i += 16) {
            int tl = s_active[i];
            float cov = s_cov[tl];
            uint4 q = *(const uint4*)(s_enc + (size_t)tl * U + u);
            float e[8]; unpack8(q, e);
            float acc = 0.f;
            #pragma unroll
            for (int j = 0; j < 8; j++)
                acc += vv[j] * tanh_fast(fmaf(cov, wc[j], e[j] + df[j]));
            acc = wave_reduce_sum(acc);
            if (lane == 0) mub[g * 128 + tl] = acc;
        }

        batch_sync(cbp, 8 * (2 * s + 1));

        // ---- softmax stats (redundant per block) from global mu
        float m1 = mub[tid];
        float wmax = wave_reduce_max(m1);
        if (lane == 0) s_red[w] = wmax;
        __syncthreads();
        float mx = s_red[0];
        #pragma unroll
        for (int i = 1; i < 16; i++) mx = fmaxf(mx, s_red[i]);
        __syncthreads();
        float e1 = EXP2F((m1 - mx) * L2E);        // masked (SENTINEL) -> 0
        float wsum = wave_reduce_sum(e1);
        if (lane == 0) s_red[w] = wsum;
        __syncthreads();
        float tot = 0.f;
        #pragma unroll
        for (int i = 0; i < 16; i++) tot += s_red[i];
        float a_t = e1 * RCPF(tot);
        s_alpha[tid] = a_t;
        __syncthreads();

        // ---- own-row outputs: alphas, covloss, coverage update (LDS-local)
        if (tid < 128) {
            float a = s_alpha[g * 128 + tid];
            float cov = s_cov[tid];
            size_t rowo = ((size_t)b * TD + s) * TE + g * 128;
            alphas[rowo + tid] = a;
            covl[rowo + tid]   = fminf(cov, a);
            s_cov[tid] = cov + a;
        }

        // ---- partial ctx over own 128 rows x all 512 e (en from L2)
        {
            const int e2 = tid & 255;            // e-pair index, e = 2*e2
            const int tq = tid >> 8;             // wave-uniform row quarter
            float a0 = 0.f, a1 = 0.f;
            const unsigned short* ep = enb + (size_t)(g * 128 + tq * 32) * DE + 2 * e2;
            for (int r = 0; r < 32; r++) {
                float a = s_alpha[g * 128 + tq * 32 + r];
                if (a != 0.f) {                  // wave-uniform: masked -> exactly 0
                    unsigned q = *(const unsigned*)ep;
                    a0 = fmaf(a, bflo(q), a0);
                    a1 = fmaf(a, bfhi(q), a1);
                }
                ep += DE;
            }
            s_pctx[tq][e2] = make_float2(a0, a1);
        }
        __syncthreads();
        if (tid < 256) {
            float2 p0 = s_pctx[0][tid], p1 = s_pctx[1][tid];
            float2 p2 = s_pctx[2][tid], p3 = s_pctx[3][tid];
            float2 r = make_float2(p0.x + p1.x + p2.x + p3.x,
                                   p0.y + p1.y + p2.y + p3.y);
            float* pw = pctx + ((size_t)(s & 1) * B * 8 + (size_t)b * 8 + g) * 512;
            *(float2*)(pw + 2 * tid) = r;
        }

        batch_sync(cbp, 8 * (2 * s + 2));
    }

    // ---- final ctx reduce for s = TD-1
    if (w == 0) {
        const float* pp = pctx + ((size_t)((TD - 1) & 1) * B * 8 + (size_t)b * 8) * 512;
        float ts = 0.f;
        #pragma unroll
        for (int gg = 0; gg < 8; gg++) ts += pp[gg * 512 + g * 64 + lane];
        out[((size_t)b * TD + (TD - 1)) * (DD + DE) + DD + g * 64 + lane] = ts;
    }
}

// ---------------------------------------------------------------------------
extern "C" void kernel_launch(void* const* d_in, const int* in_sizes, int n_in,
                              void* d_out, int out_size, void* d_ws, size_t ws_size,
                              hipStream_t stream) {
    const float* en_seq = (const float*)d_in[0];
    const float* de_seq = (const float*)d_in[1];
    const int*   mask   = (const int*)d_in[2];
    const float* W_h    = (const float*)d_in[3];
    const float* W_s    = (const float*)d_in[4];
    const float* w_c    = (const float*)d_in[5];
    const float* v      = (const float*)d_in[6];
    float* out = (float*)d_out;

    // workspace layout (~67.3 MiB)
    unsigned short* enc_bf = (unsigned short*)d_ws;        // B*TE*U  bf16 = 32 MiB
    unsigned short* en_bf  = enc_bf + (size_t)B * TE * U;  // B*TE*DE bf16 = 32 MiB
    unsigned short* dec_bf = en_bf  + (size_t)B * TE * DE; // B*TD*U  bf16 = 2 MiB
    float* mu   = (float*)(dec_bf + (size_t)B * TD * U);   // B*TE
    float* pctx = mu + (size_t)B * TE;                     // 2*B*8*512 = 1 MiB
    int*   cnt  = (int*)(pctx + (size_t)2 * B * 8 * 512);  // 512 ints

    k_init<<<128, 256, 0, stream>>>(mu, cnt);
    k_cast<<<16384, 256, 0, stream>>>((const float4*)en_seq, (ushort4*)en_bf);
    k_pass<<<1024, 256, 0, stream>>>((const float4*)de_seq, (float4*)out);
    k_gemm_bf<<<dim3(U / 64, (B * TE) / 64), 256, 0, stream>>>(en_seq, W_h, enc_bf);
    k_gemm_bf<<<dim3(U / 64, (B * TD) / 64), 256, 0, stream>>>(de_seq, W_s, dec_bf);

    void* args[] = { (void*)&enc_bf, (void*)&dec_bf, (void*)&en_bf,
                     (void*)&w_c, (void*)&v, (void*)&mask,
                     (void*)&mu, (void*)&pctx, (void*)&cnt, (void*)&out };
    hipLaunchCooperativeKernel((const void*)k_scan, dim3(256), dim3(1024),
                               args, 0, stream);
}

// Round 4
// 1259.454 us; speedup vs baseline: 3.3895x; 1.7846x over previous
//
#include <hip/hip_runtime.h>
#include <float.h>

// Problem constants
#define B   32
#define TE  1024
#define TD  64
#define DE  512
#define DD  512
#define U   512
#define K   512   // == DE == DD

#if __has_builtin(__builtin_amdgcn_exp2f)
#define EXP2F __builtin_amdgcn_exp2f
#else
#define EXP2F exp2f
#endif
#if __has_builtin(__builtin_amdgcn_rcpf)
#define RCPF __builtin_amdgcn_rcpf
#else
#define RCPF(x) (1.0f / (x))
#endif

#define SENTINEL -1e30f

__device__ __forceinline__ float tanh_fast(float x) {
    float e = EXP2F(x * 2.8853900817779268f);   // e^{2x}
    return 1.0f - 2.0f * RCPF(e + 1.0f);        // saturates correctly at +-inf
}

__device__ __forceinline__ float wave_reduce_sum(float v) {
    #pragma unroll
    for (int o = 32; o; o >>= 1) v += __shfl_xor(v, o, 64);
    return v;
}
__device__ __forceinline__ float wave_reduce_max(float v) {
    #pragma unroll
    for (int o = 32; o; o >>= 1) v = fmaxf(v, __shfl_xor(v, o, 64));
    return v;
}

// f32 -> bf16 RNE
__device__ __forceinline__ unsigned short f2bf(float f) {
    unsigned u = __float_as_uint(f);
    unsigned r = (u + 0x7fffu + ((u >> 16) & 1u)) >> 16;
    return (unsigned short)r;
}
__device__ __forceinline__ float bflo(unsigned x) { return __uint_as_float(x << 16); }
__device__ __forceinline__ float bfhi(unsigned x) { return __uint_as_float(x & 0xffff0000u); }
__device__ __forceinline__ void unpack8(uint4 q, float* f) {
    f[0] = bflo(q.x); f[1] = bfhi(q.x); f[2] = bflo(q.y); f[3] = bfhi(q.y);
    f[4] = bflo(q.z); f[5] = bfhi(q.z); f[6] = bflo(q.w); f[7] = bfhi(q.w);
}

// relaxed agent-scope (IC-level) accessors: per-instruction cache bypass,
// no wbl2/inv cache maintenance.
__device__ __forceinline__ float ld_agent(const float* p) {
    return __hip_atomic_load(p, __ATOMIC_RELAXED, __HIP_MEMORY_SCOPE_AGENT);
}
__device__ __forceinline__ void st_agent(float* p, float v) {
    __hip_atomic_store(p, v, __ATOMIC_RELAXED, __HIP_MEMORY_SCOPE_AGENT);
}

// ---------------------------------------------------------------------------
// init: mu (both parity buffers) = SENTINEL, sync counters = 0
__global__ __launch_bounds__(256) void k_init(float* __restrict__ mu,
                                              int* __restrict__ cnt) {
    int i = blockIdx.x * 256 + threadIdx.x;   // grid 256*256 = 65536
    mu[i] = SENTINEL;
    if (i < 1024) cnt[i] = 0;
}

// en_seq f32 -> bf16
__global__ __launch_bounds__(256) void k_cast(const float4* __restrict__ in,
                                              ushort4* __restrict__ outp) {
    size_t i = (size_t)blockIdx.x * 256 + threadIdx.x;
    float4 f = in[i];
    ushort4 r;
    r.x = f2bf(f.x); r.y = f2bf(f.y); r.z = f2bf(f.z); r.w = f2bf(f.w);
    outp[i] = r;
}

// de_seq passthrough into out[:, :, 0:DD]
__global__ __launch_bounds__(256) void k_pass(const float4* __restrict__ de,
                                              float4* __restrict__ outp) {
    size_t i = (size_t)blockIdx.x * 256 + threadIdx.x;  // 262144 float4
    size_t r = i >> 7, c = i & 127;
    outp[r * 256 + c] = de[i];
}

// ---------------------------------------------------------------------------
// C_bf16[M,512] = A[M,512] @ W[512,512].  64x64 tile, BK=16, 256 thr, 4x4/thr
__global__ __launch_bounds__(256) void k_gemm_bf(const float* __restrict__ A,
                                                 const float* __restrict__ W,
                                                 unsigned short* __restrict__ C) {
    __shared__ __align__(16) float As[16][68];
    __shared__ __align__(16) float Bs[16][64];
    const int tid = threadIdx.x;
    const int tx = tid & 15;
    const int ty = tid >> 4;
    const int m0 = blockIdx.y * 64;
    const int n0 = blockIdx.x * 64;

    float acc[4][4];
    #pragma unroll
    for (int i = 0; i < 4; i++)
        #pragma unroll
        for (int j = 0; j < 4; j++) acc[i][j] = 0.f;

    for (int k0 = 0; k0 < K; k0 += 16) {
        #pragma unroll
        for (int i = 0; i < 4; i++) {
            int id = i * 256 + tid;
            int m = id >> 4, kk = id & 15;
            As[kk][m] = A[(size_t)(m0 + m) * K + k0 + kk];
        }
        #pragma unroll
        for (int i = 0; i < 4; i++) {
            int id = i * 256 + tid;
            int n = id & 63, kk = id >> 6;
            Bs[kk][n] = W[(size_t)(k0 + kk) * U + n0 + n];
        }
        __syncthreads();
        #pragma unroll
        for (int kk = 0; kk < 16; kk++) {
            float4 a4 = *(const float4*)&As[kk][ty * 4];
            float4 b4 = *(const float4*)&Bs[kk][tx * 4];
            float a[4] = {a4.x, a4.y, a4.z, a4.w};
            float b[4] = {b4.x, b4.y, b4.z, b4.w};
            #pragma unroll
            for (int i = 0; i < 4; i++)
                #pragma unroll
                for (int j = 0; j < 4; j++) acc[i][j] += a[i] * b[j];
        }
        __syncthreads();
    }
    #pragma unroll
    for (int i = 0; i < 4; i++) {
        ushort4 r;
        r.x = f2bf(acc[i][0]); r.y = f2bf(acc[i][1]);
        r.z = f2bf(acc[i][2]); r.w = f2bf(acc[i][3]);
        *(ushort4*)&C[(size_t)(m0 + ty * 4 + i) * U + n0 + tx * 4] = r;
    }
}

// ---------------------------------------------------------------------------
// per-batch sync among the 8 blocks of batch b. Monotone counter, never reset.
// RELAXED everywhere: the preceding __syncthreads drains every wave's
// outstanding stores (compiler emits s_waitcnt vmcnt(0) before s_barrier),
// and all cross-block data uses agent-scope (IC) stores/loads, so no
// wbl2/inv cache maintenance is needed.
__device__ __forceinline__ void batch_sync(int* c, int target) {
    __syncthreads();
    if (threadIdx.x == 0) {
        __hip_atomic_fetch_add(c, 1, __ATOMIC_RELAXED, __HIP_MEMORY_SCOPE_AGENT);
        while (__hip_atomic_load(c, __ATOMIC_RELAXED, __HIP_MEMORY_SCOPE_AGENT) < target)
            __builtin_amdgcn_s_sleep(2);
    }
    __syncthreads();
}

// ---------------------------------------------------------------------------
// Persistent scan: 256 blocks x 1024 threads, cooperative.
// block -> (b = blk&31, g = blk>>5) so a batch's 8 blocks share an XCD under
// round-robin dispatch (speed heuristic only). Block owns t-rows
// [g*128, g*128+128); enc slice lives in LDS (128 KB, loaded once).
// ONE sync per step; mu and pctx double-buffered by step parity:
//   phase1: mu(s) own rows -> mu_buf[s&1]      (agent stores)
//   sync(s)
//   phase3: reduce pctx(s-1) -> out ctx        (agent loads; complete because
//           all blocks wrote pctx(s-1) before arriving at sync(s))
//   phase4: softmax over mu_buf[s&1]           (agent loads)
//   phase5: own-row alphas/covloss/cov update
//   phase6: partial ctx -> pctx_buf[s&1]       (agent stores)
// Buffer-reuse races are excluded by the sync cadence: parity buffer X of
// step s is fully read before any block can pass sync(s+1) and rewrite it.
__global__ __launch_bounds__(1024, 4) void k_scan(
        const unsigned short* __restrict__ enc_bf,
        const unsigned short* __restrict__ dec_bf,
        const unsigned short* __restrict__ en_bf,
        const float* __restrict__ w_c,
        const float* __restrict__ v,
        const int* __restrict__ mask,
        float* __restrict__ mu,       // [2][B][TE]
        float* __restrict__ pctx,     // [2][B][8][512]
        int* __restrict__ cnt,
        float* __restrict__ out)
{
    const int blk = blockIdx.x;
    const int b = blk & 31, g = blk >> 5;     // XCD-local batch grouping
    const int tid = threadIdx.x;
    const int w = tid >> 6, lane = tid & 63;
    const int u = lane * 8;
    const float L2E = 1.4426950408889634f;

    __shared__ __align__(16) unsigned short s_enc[128 * U];  // 128 KiB
    __shared__ float  s_alpha[TE];                           // 4 KiB
    __shared__ float2 s_pctx[4][256];                        // 8 KiB
    __shared__ float  s_red[16];
    __shared__ float  s_cov[128];
    __shared__ int    s_active[128];
    __shared__ int    s_cnt[2];
    __shared__ int    s_nact;

    const int*   maskb = mask + b * TE;
    const unsigned short* encb = enc_bf + ((size_t)b * TE + g * 128) * U;
    const unsigned short* enb  = en_bf  + (size_t)b * TE * DE;
    int* cbp = cnt + b * 32;                  // 128 B spacing, no false sharing
    float* alphas = out + (size_t)B * TD * (DD + DE);
    float* covl   = alphas + (size_t)B * TD * TE;

    // lane-resident w_c / v fragments
    float wc[8], vv[8];
    {
        float4 a0 = *(const float4*)&w_c[u];
        float4 a1 = *(const float4*)&w_c[u + 4];
        wc[0]=a0.x; wc[1]=a0.y; wc[2]=a0.z; wc[3]=a0.w;
        wc[4]=a1.x; wc[5]=a1.y; wc[6]=a1.z; wc[7]=a1.w;
        float4 b0 = *(const float4*)&v[u];
        float4 b1 = *(const float4*)&v[u + 4];
        vv[0]=b0.x; vv[1]=b0.y; vv[2]=b0.z; vv[3]=b0.w;
        vv[4]=b1.x; vv[5]=b1.y; vv[6]=b1.z; vv[7]=b1.w;
    }

    // stage own enc slice into LDS: 131072 B = 8192 uint4, 8 iters
    {
        const uint4* src = (const uint4*)encb;
        uint4* dst = (uint4*)s_enc;
        #pragma unroll
        for (int i = 0; i < 8; i++) dst[i * 1024 + tid] = src[i * 1024 + tid];
    }

    // active-row compaction (ballot) + coverage init
    {
        int act = 0;
        if (tid < 128) act = (maskb[g * 128 + tid] != 0);
        unsigned long long bal = __ballot(act);
        int pre = __popcll(bal & ((1ull << lane) - 1));
        if (w < 2 && lane == 0) s_cnt[w] = __popcll(bal);
        if (tid < 128) s_cov[tid] = 0.f;
        __syncthreads();
        if (act) {
            int base = (w == 1) ? s_cnt[0] : 0;
            s_active[base + pre] = tid;       // t_local
        }
        if (tid == 0) s_nact = s_cnt[0] + s_cnt[1];
        __syncthreads();
    }
    const int n_act = s_nact;

    for (int s = 0; s < TD; s++) {
        float* mub = mu + (size_t)(s & 1) * B * TE + (size_t)b * TE;

        // ---- dec fragment for (b,s)
        float df[8];
        {
            uint4 q = *(const uint4*)(dec_bf + (((size_t)b * TD + s) * U + u));
            unpack8(q, df);
        }

        // ---- phase 1: mu over active own rows (enc from LDS)
        for (int i = w; i < n_act; i += 16) {
            int tl = s_active[i];
            float cov = s_cov[tl];
            uint4 q = *(const uint4*)(s_enc + (size_t)tl * U + u);
            float e[8]; unpack8(q, e);
            float acc = 0.f;
            #pragma unroll
            for (int j = 0; j < 8; j++)
                acc += vv[j] * tanh_fast(fmaf(cov, wc[j], e[j] + df[j]));
            acc = wave_reduce_sum(acc);
            if (lane == 0) st_agent(&mub[g * 128 + tl], acc);
        }

        batch_sync(cbp, 8 * (s + 1));

        // ---- phase 3: deferred ctx reduce for step s-1
        if (s > 0 && w == 0) {
            const float* pp = pctx + ((size_t)((s - 1) & 1) * B * 8 + (size_t)b * 8) * 512;
            float ts = 0.f;
            #pragma unroll
            for (int gg = 0; gg < 8; gg++) ts += ld_agent(&pp[gg * 512 + g * 64 + lane]);
            out[((size_t)b * TD + (s - 1)) * (DD + DE) + DD + g * 64 + lane] = ts;
        }

        // ---- phase 4: softmax stats (redundant per block), mu from IC
        float m1 = ld_agent(&mub[tid]);
        float wmax = wave_reduce_max(m1);
        if (lane == 0) s_red[w] = wmax;
        __syncthreads();
        float mx = s_red[0];
        #pragma unroll
        for (int i = 1; i < 16; i++) mx = fmaxf(mx, s_red[i]);
        __syncthreads();
        float e1 = EXP2F((m1 - mx) * L2E);        // masked (SENTINEL) -> 0
        float wsum = wave_reduce_sum(e1);
        if (lane == 0) s_red[w] = wsum;
        __syncthreads();
        float tot = 0.f;
        #pragma unroll
        for (int i = 0; i < 16; i++) tot += s_red[i];
        float a_t = e1 * RCPF(tot);
        s_alpha[tid] = a_t;
        __syncthreads();

        // ---- phase 5: own-row outputs (alphas/covloss/cov, LDS-local cov)
        if (tid < 128) {
            float a = s_alpha[g * 128 + tid];
            float cov = s_cov[tid];
            size_t rowo = ((size_t)b * TD + s) * TE + g * 128;
            alphas[rowo + tid] = a;
            covl[rowo + tid]   = fminf(cov, a);
            s_cov[tid] = cov + a;
        }

        // ---- phase 6: partial ctx over own 128 rows x all 512 e (en from L2)
        {
            const int e2 = tid & 255;            // e-pair index, e = 2*e2
            const int tq = tid >> 8;             // wave-uniform row quarter
            float a0 = 0.f, a1 = 0.f;
            const unsigned short* ep = enb + (size_t)(g * 128 + tq * 32) * DE + 2 * e2;
            for (int r = 0; r < 32; r++) {
                float a = s_alpha[g * 128 + tq * 32 + r];
                if (a != 0.f) {                  // wave-uniform: masked -> exactly 0
                    unsigned q = *(const unsigned*)ep;
                    a0 = fmaf(a, bflo(q), a0);
                    a1 = fmaf(a, bfhi(q), a1);
                }
                ep += DE;
            }
            s_pctx[tq][e2] = make_float2(a0, a1);
        }
        __syncthreads();
        if (tid < 256) {
            float2 p0 = s_pctx[0][tid], p1 = s_pctx[1][tid];
            float2 p2 = s_pctx[2][tid], p3 = s_pctx[3][tid];
            float* pw = pctx + ((size_t)(s & 1) * B * 8 + (size_t)b * 8 + g) * 512;
            st_agent(&pw[2 * tid],     p0.x + p1.x + p2.x + p3.x);
            st_agent(&pw[2 * tid + 1], p0.y + p1.y + p2.y + p3.y);
        }
    }

    // ---- final: sync once more, then reduce pctx(TD-1)
    batch_sync(cbp, 8 * (TD + 1));
    if (w == 0) {
        const float* pp = pctx + ((size_t)((TD - 1) & 1) * B * 8 + (size_t)b * 8) * 512;
        float ts = 0.f;
        #pragma unroll
        for (int gg = 0; gg < 8; gg++) ts += ld_agent(&pp[gg * 512 + g * 64 + lane]);
        out[((size_t)b * TD + (TD - 1)) * (DD + DE) + DD + g * 64 + lane] = ts;
    }
}

// ---------------------------------------------------------------------------
extern "C" void kernel_launch(void* const* d_in, const int* in_sizes, int n_in,
                              void* d_out, int out_size, void* d_ws, size_t ws_size,
                              hipStream_t stream) {
    const float* en_seq = (const float*)d_in[0];
    const float* de_seq = (const float*)d_in[1];
    const int*   mask   = (const int*)d_in[2];
    const float* W_h    = (const float*)d_in[3];
    const float* W_s    = (const float*)d_in[4];
    const float* w_c    = (const float*)d_in[5];
    const float* v      = (const float*)d_in[6];
    float* out = (float*)d_out;

    // workspace layout (~67.6 MiB)
    unsigned short* enc_bf = (unsigned short*)d_ws;        // B*TE*U  bf16 = 32 MiB
    unsigned short* en_bf  = enc_bf + (size_t)B * TE * U;  // B*TE*DE bf16 = 32 MiB
    unsigned short* dec_bf = en_bf  + (size_t)B * TE * DE; // B*TD*U  bf16 = 2 MiB
    float* mu   = (float*)(dec_bf + (size_t)B * TD * U);   // 2*B*TE
    float* pctx = mu + (size_t)2 * B * TE;                 // 2*B*8*512 = 1 MiB
    int*   cnt  = (int*)(pctx + (size_t)2 * B * 8 * 512);  // 1024 ints

    k_init<<<256, 256, 0, stream>>>(mu, cnt);
    k_cast<<<16384, 256, 0, stream>>>((const float4*)en_seq, (ushort4*)en_bf);
    k_pass<<<1024, 256, 0, stream>>>((const float4*)de_seq, (float4*)out);
    k_gemm_bf<<<dim3(U / 64, (B * TE) / 64), 256, 0, stream>>>(en_seq, W_h, enc_bf);
    k_gemm_bf<<<dim3(U / 64, (B * TD) / 64), 256, 0, stream>>>(de_seq, W_s, dec_bf);

    void* args[] = { (void*)&enc_bf, (void*)&dec_bf, (void*)&en_bf,
                     (void*)&w_c, (void*)&v, (void*)&mask,
                     (void*)&mu, (void*)&pctx, (void*)&cnt, (void*)&out };
    hipLaunchCooperativeKernel((const void*)k_scan, dim3(256), dim3(1024),
                               args, 0, stream);
}

// Round 6
// 895.337 us; speedup vs baseline: 4.7679x; 1.4067x over previous
//
#include <hip/hip_runtime.h>
#include <float.h>

// Problem constants
#define B   32
#define TE  1024
#define TD  64
#define DE  512
#define DD  512
#define U   512
#define K   512   // == DE == DD
#define NB  8     // blocks per batch (256-block coop launch: proven geometry)
#define RPB 128   // t-rows per block

#if __has_builtin(__builtin_amdgcn_exp2f)
#define EXP2F __builtin_amdgcn_exp2f
#else
#define EXP2F exp2f
#endif
#if __has_builtin(__builtin_amdgcn_rcpf)
#define RCPF __builtin_amdgcn_rcpf
#else
#define RCPF(x) (1.0f / (x))
#endif

#define SENTINEL -1e30f

__device__ __forceinline__ float tanh_fast(float x) {
    float e = EXP2F(x * 2.8853900817779268f);   // e^{2x}
    return 1.0f - 2.0f * RCPF(e + 1.0f);        // saturates correctly at +-inf
}

__device__ __forceinline__ float wave_reduce_sum(float v) {
    #pragma unroll
    for (int o = 32; o; o >>= 1) v += __shfl_xor(v, o, 64);
    return v;
}

// f32 -> bf16 RNE
__device__ __forceinline__ unsigned short f2bf(float f) {
    unsigned u = __float_as_uint(f);
    unsigned r = (u + 0x7fffu + ((u >> 16) & 1u)) >> 16;
    return (unsigned short)r;
}
__device__ __forceinline__ float bflo(unsigned x) { return __uint_as_float(x << 16); }
__device__ __forceinline__ float bfhi(unsigned x) { return __uint_as_float(x & 0xffff0000u); }
__device__ __forceinline__ void unpack8(uint4 q, float* f) {
    f[0] = bflo(q.x); f[1] = bfhi(q.x); f[2] = bflo(q.y); f[3] = bfhi(q.y);
    f[4] = bflo(q.z); f[5] = bfhi(q.z); f[6] = bflo(q.w); f[7] = bfhi(q.w);
}

// relaxed agent-scope (IC-level) accessors: per-instruction cache bypass,
// no wbl2/inv cache maintenance.
__device__ __forceinline__ float ld_agent(const float* p) {
    return __hip_atomic_load(p, __ATOMIC_RELAXED, __HIP_MEMORY_SCOPE_AGENT);
}
__device__ __forceinline__ void st_agent(float* p, float v) {
    __hip_atomic_store(p, v, __ATOMIC_RELAXED, __HIP_MEMORY_SCOPE_AGENT);
}
__device__ __forceinline__ unsigned long long ld_agent64(const unsigned long long* p) {
    return __hip_atomic_load(p, __ATOMIC_RELAXED, __HIP_MEMORY_SCOPE_AGENT);
}
__device__ __forceinline__ void st_agent64(unsigned long long* p, unsigned long long v) {
    __hip_atomic_store(p, v, __ATOMIC_RELAXED, __HIP_MEMORY_SCOPE_AGENT);
}

// ---------------------------------------------------------------------------
// init: stats tags = 0 (2*B*NB = 512 u64)
__global__ __launch_bounds__(256) void k_init(unsigned long long* __restrict__ stats) {
    int i = blockIdx.x * 256 + threadIdx.x;   // grid 2*256 = 512
    stats[i] = 0ull;
}

// en_seq f32 -> bf16
__global__ __launch_bounds__(256) void k_cast(const float4* __restrict__ in,
                                              ushort4* __restrict__ outp) {
    size_t i = (size_t)blockIdx.x * 256 + threadIdx.x;
    float4 f = in[i];
    ushort4 r;
    r.x = f2bf(f.x); r.y = f2bf(f.y); r.z = f2bf(f.z); r.w = f2bf(f.w);
    outp[i] = r;
}

// de_seq passthrough into out[:, :, 0:DD]
__global__ __launch_bounds__(256) void k_pass(const float4* __restrict__ de,
                                              float4* __restrict__ outp) {
    size_t i = (size_t)blockIdx.x * 256 + threadIdx.x;  // 262144 float4
    size_t r = i >> 7, c = i & 127;
    outp[r * 256 + c] = de[i];
}

// ---------------------------------------------------------------------------
// C_bf16[M,512] = A[M,512] @ W[512,512].  64x64 tile, BK=16, 256 thr, 4x4/thr
__global__ __launch_bounds__(256) void k_gemm_bf(const float* __restrict__ A,
                                                 const float* __restrict__ W,
                                                 unsigned short* __restrict__ C) {
    __shared__ __align__(16) float As[16][68];
    __shared__ __align__(16) float Bs[16][64];
    const int tid = threadIdx.x;
    const int tx = tid & 15;
    const int ty = tid >> 4;
    const int m0 = blockIdx.y * 64;
    const int n0 = blockIdx.x * 64;

    float acc[4][4];
    #pragma unroll
    for (int i = 0; i < 4; i++)
        #pragma unroll
        for (int j = 0; j < 4; j++) acc[i][j] = 0.f;

    for (int k0 = 0; k0 < K; k0 += 16) {
        #pragma unroll
        for (int i = 0; i < 4; i++) {
            int id = i * 256 + tid;
            int m = id >> 4, kk = id & 15;
            As[kk][m] = A[(size_t)(m0 + m) * K + k0 + kk];
        }
        #pragma unroll
        for (int i = 0; i < 4; i++) {
            int id = i * 256 + tid;
            int n = id & 63, kk = id >> 6;
            Bs[kk][n] = W[(size_t)(k0 + kk) * U + n0 + n];
        }
        __syncthreads();
        #pragma unroll
        for (int kk = 0; kk < 16; kk++) {
            float4 a4 = *(const float4*)&As[kk][ty * 4];
            float4 b4 = *(const float4*)&Bs[kk][tx * 4];
            float a[4] = {a4.x, a4.y, a4.z, a4.w};
            float b[4] = {b4.x, b4.y, b4.z, b4.w};
            #pragma unroll
            for (int i = 0; i < 4; i++)
                #pragma unroll
                for (int j = 0; j < 4; j++) acc[i][j] += a[i] * b[j];
        }
        __syncthreads();
    }
    #pragma unroll
    for (int i = 0; i < 4; i++) {
        ushort4 r;
        r.x = f2bf(acc[i][0]); r.y = f2bf(acc[i][1]);
        r.z = f2bf(acc[i][2]); r.w = f2bf(acc[i][3]);
        *(ushort4*)&C[(size_t)(m0 + ty * 4 + i) * U + n0 + tx * 4] = r;
    }
}

// ---------------------------------------------------------------------------
// Persistent scan: 256 blocks x 1024 threads, cooperative (proven geometry).
// block -> (b = blk&31, g = blk>>5): a batch's 8 blocks share an XCD under
// round-robin dispatch (heuristic). Block owns t-rows [g*128, g*128+128);
// its enc slice lives in LDS (128 KB, loaded once).
// No max-subtraction softmax: |mu| <= sum|v| ~ 18, exp2(mu*log2e) is safe in
// f32, so each block publishes ONE u64 (sum_g:f32 | tag:u32=s+1) per step.
// The tag is both arrival signal and data: one IC RTT for sync+reduction.
// pctx(s-1) visibility: each block's pre-publish __syncthreads drains
// vmcnt(0) (compiler-emitted; acks at coherence point for sc1 stores), so
// tag==s+1 from all 8 blocks implies all pctx(s-1) stores are IC-visible.
// (Validated mechanism: round 4 used the same chain with a counter.)
__global__ __launch_bounds__(1024, 4) void k_scan(
        const unsigned short* __restrict__ enc_bf,
        const unsigned short* __restrict__ dec_bf,
        const unsigned short* __restrict__ en_bf,
        const float* __restrict__ w_c,
        const float* __restrict__ v,
        const int* __restrict__ mask,
        unsigned long long* __restrict__ stats,  // [2][B][NB]
        float* __restrict__ pctx,                // [2][B][NB][512]
        float* __restrict__ out)
{
    const int blk = blockIdx.x;
    const int b = blk & 31, g = blk >> 5;    // XCD-local batch grouping
    const int tid = threadIdx.x;
    const int w = tid >> 6, lane = tid & 63;
    const int u = lane * 8;
    const float L2E = 1.4426950408889634f;

    __shared__ __align__(16) unsigned short s_enc[RPB * U];  // 128 KiB
    __shared__ float  s_mu[RPB];
    __shared__ float  s_alpha[RPB];
    __shared__ float  s_cov[RPB];
    __shared__ int    s_active[RPB];
    __shared__ float  s_wsum[16];
    __shared__ float  s_cred[NB][64];        // 2 KiB
    __shared__ float2 s_p6[4][256];          // 8 KiB
    __shared__ float  s_inv;
    __shared__ int    s_nact;

    const int* maskb = mask + b * TE;
    const unsigned short* encb = enc_bf + ((size_t)b * TE + g * RPB) * U;
    float* alphas = out + (size_t)B * TD * (DD + DE);
    float* covl   = alphas + (size_t)B * TD * TE;

    // lane-resident w_c / v fragments
    float wc[8], vv[8];
    {
        float4 a0 = *(const float4*)&w_c[u];
        float4 a1 = *(const float4*)&w_c[u + 4];
        wc[0]=a0.x; wc[1]=a0.y; wc[2]=a0.z; wc[3]=a0.w;
        wc[4]=a1.x; wc[5]=a1.y; wc[6]=a1.z; wc[7]=a1.w;
        float4 b0 = *(const float4*)&v[u];
        float4 b1 = *(const float4*)&v[u + 4];
        vv[0]=b0.x; vv[1]=b0.y; vv[2]=b0.z; vv[3]=b0.w;
        vv[4]=b1.x; vv[5]=b1.y; vv[6]=b1.z; vv[7]=b1.w;
    }

    // stage own enc slice into LDS: 131072 B = 8192 uint4, 8 iters
    {
        const uint4* src = (const uint4*)encb;
        uint4* dst = (uint4*)s_enc;
        #pragma unroll
        for (int i = 0; i < 8; i++) dst[i * 1024 + tid] = src[i * 1024 + tid];
    }

    // active-row compaction (waves 0-1, 128 rows), mu/cov init
    {
        int act = 0;
        if (tid < RPB) act = (maskb[g * RPB + tid] != 0);
        unsigned long long bal = __ballot(act);
        int pre = __popcll(bal & ((1ull << lane) - 1));
        __shared__ int s_c2[2];
        if (w < 2 && lane == 0) s_c2[w] = __popcll(bal);
        if (tid < RPB) { s_mu[tid] = SENTINEL; s_cov[tid] = 0.f; }
        __syncthreads();
        if (act) {
            int base = (w == 1) ? s_c2[0] : 0;
            s_active[base + pre] = tid;
        }
        if (tid == 0) s_nact = s_c2[0] + s_c2[1];
        __syncthreads();
    }
    const int n_act = s_nact;

    for (int s = 0; s < TD; s++) {
        // ---- dec fragment for (b,s)
        float df[8];
        {
            uint4 q = *(const uint4*)(dec_bf + (((size_t)b * TD + s) * U + u));
            unpack8(q, df);
        }

        // ---- phase 1: mu over own active rows (enc from LDS) + local expsum
        float local_esum = 0.f;
        for (int i = w; i < n_act; i += 16) {
            int r = s_active[i];
            float cov = s_cov[r];
            uint4 q = *(const uint4*)(s_enc + (size_t)r * U + u);
            float e[8]; unpack8(q, e);
            float acc = 0.f;
            #pragma unroll
            for (int j = 0; j < 8; j++)
                acc += vv[j] * tanh_fast(fmaf(cov, wc[j], e[j] + df[j]));
            acc = wave_reduce_sum(acc);
            if (lane == 0) s_mu[r] = acc;
            local_esum += EXP2F(acc * L2E);
        }
        if (lane == 0) s_wsum[w] = local_esum;

        __syncthreads();   // B1: drains pctx(s-1) agent-stores (vmcnt(0))

        // ---- publish (sum_g | tag s+1), poll all 8 tags (wave 0 only)
        if (w == 0) {
            float sg = (lane < 16) ? s_wsum[lane] : 0.f;
            sg = wave_reduce_sum(sg);
            unsigned long long* sl = stats + ((size_t)(s & 1) * B + b) * NB;
            if (lane == 0) {
                unsigned long long pv =
                    ((unsigned long long)__float_as_uint(sg) << 32) |
                    (unsigned)(s + 1);
                st_agent64(&sl[g], pv);
            }
            unsigned long long pv = 0;
            for (;;) {
                if (lane < NB) pv = ld_agent64(&sl[lane]);
                unsigned long long okm =
                    __ballot(lane < NB ? ((unsigned)pv == (unsigned)(s + 1)) : 1);
                if (~okm == 0ull) break;
                __builtin_amdgcn_s_sleep(1);
            }
            float tg = (lane < NB) ? __uint_as_float((unsigned)(pv >> 32)) : 0.f;
            tg = wave_reduce_sum(tg);
            if (lane == 0) s_inv = RCPF(tg);
        }
        __syncthreads();   // B2

        const float inv = s_inv;

        // ---- deferred ctx(s-1) partial loads (IC)  [threads 0..511]
        if (s > 0 && tid < 512) {
            int gg = tid >> 6, e = tid & 63;
            s_cred[gg][e] = ld_agent(
                &pctx[(((size_t)((s - 1) & 1) * B + b) * NB + gg) * 512 + g * 64 + e]);
        }
        // ---- own-row alpha/cov/outputs  [threads 512..639]
        if (tid >= 512 && tid < 512 + RPB) {
            int r = tid - 512;
            float a = EXP2F(s_mu[r] * L2E) * inv;   // masked -> exactly 0
            float cov = s_cov[r];
            size_t rowo = ((size_t)b * TD + s) * TE + g * RPB + r;
            alphas[rowo] = a;
            covl[rowo]   = fminf(cov, a);
            s_alpha[r] = a;
            s_cov[r] = cov + a;
        }
        __syncthreads();   // B3

        // ---- ctx(s-1) final reduce + store  [threads 0..63]
        if (s > 0 && tid < 64) {
            float ts = 0.f;
            #pragma unroll
            for (int gg = 0; gg < NB; gg++) ts += s_cred[gg][tid];
            out[((size_t)b * TD + (s - 1)) * (DD + DE) + DD + g * 64 + tid] = ts;
        }

        // ---- phase 6: partial ctx, own 128 rows x 512 e, branchless unrolled
        {
            const int e2 = tid & 255, q = tid >> 8;   // 256 e-pairs x 4 quarters
            const unsigned* ep = (const unsigned*)
                (en_bf + ((size_t)b * TE + g * RPB + q * 32) * DE) + e2;
            float a0 = 0.f, a1 = 0.f;
            #pragma unroll
            for (int r = 0; r < 32; r++) {
                float a = s_alpha[q * 32 + r];
                unsigned qq = ep[(size_t)r * (DE / 2)];
                a0 = fmaf(a, bflo(qq), a0);           // masked: a==0 exact
                a1 = fmaf(a, bfhi(qq), a1);
            }
            s_p6[q][e2] = make_float2(a0, a1);
        }
        __syncthreads();   // B4
        if (tid < 256) {
            float2 p0 = s_p6[0][tid], p1 = s_p6[1][tid];
            float2 p2 = s_p6[2][tid], p3 = s_p6[3][tid];
            float* pw = pctx + (((size_t)(s & 1) * B + b) * NB + g) * 512;
            st_agent(&pw[2 * tid],     p0.x + p1.x + p2.x + p3.x);
            st_agent(&pw[2 * tid + 1], p0.y + p1.y + p2.y + p3.y);
        }
    }

    // ---- epilogue: one more tag round, then reduce pctx(TD-1)
    __syncthreads();       // drains pctx(TD-1) stores
    if (w == 0) {
        unsigned long long* sl = stats + ((size_t)(TD & 1) * B + b) * NB;
        if (lane == 0) st_agent64(&sl[g], (unsigned long long)(TD + 1));
        unsigned long long pv = 0;
        for (;;) {
            if (lane < NB) pv = ld_agent64(&sl[lane]);
            unsigned long long okm =
                __ballot(lane < NB ? ((unsigned)pv == (unsigned)(TD + 1)) : 1);
            if (~okm == 0ull) break;
            __builtin_amdgcn_s_sleep(1);
        }
    }
    __syncthreads();
    if (tid < 512) {
        int gg = tid >> 6, e = tid & 63;
        s_cred[gg][e] = ld_agent(
            &pctx[(((size_t)((TD - 1) & 1) * B + b) * NB + gg) * 512 + g * 64 + e]);
    }
    __syncthreads();
    if (tid < 64) {
        float ts = 0.f;
        #pragma unroll
        for (int gg = 0; gg < NB; gg++) ts += s_cred[gg][tid];
        out[((size_t)b * TD + (TD - 1)) * (DD + DE) + DD + g * 64 + tid] = ts;
    }
}

// ---------------------------------------------------------------------------
extern "C" void kernel_launch(void* const* d_in, const int* in_sizes, int n_in,
                              void* d_out, int out_size, void* d_ws, size_t ws_size,
                              hipStream_t stream) {
    const float* en_seq = (const float*)d_in[0];
    const float* de_seq = (const float*)d_in[1];
    const int*   mask   = (const int*)d_in[2];
    const float* W_h    = (const float*)d_in[3];
    const float* W_s    = (const float*)d_in[4];
    const float* w_c    = (const float*)d_in[5];
    const float* v      = (const float*)d_in[6];
    float* out = (float*)d_out;

    // workspace layout (~67.1 MiB)
    unsigned short* enc_bf = (unsigned short*)d_ws;        // B*TE*U  bf16 = 32 MiB
    unsigned short* en_bf  = enc_bf + (size_t)B * TE * U;  // B*TE*DE bf16 = 32 MiB
    unsigned short* dec_bf = en_bf  + (size_t)B * TE * DE; // B*TD*U  bf16 = 2 MiB
    float* pctx = (float*)(dec_bf + (size_t)B * TD * U);   // 2*B*NB*512 f32 = 1 MiB
    unsigned long long* stats =
        (unsigned long long*)(pctx + (size_t)2 * B * NB * 512);  // 512 u64

    k_init<<<2, 256, 0, stream>>>(stats);
    k_cast<<<16384, 256, 0, stream>>>((const float4*)en_seq, (ushort4*)en_bf);
    k_pass<<<1024, 256, 0, stream>>>((const float4*)de_seq, (float4*)out);
    k_gemm_bf<<<dim3(U / 64, (B * TE) / 64), 256, 0, stream>>>(en_seq, W_h, enc_bf);
    k_gemm_bf<<<dim3(U / 64, (B * TD) / 64), 256, 0, stream>>>(de_seq, W_s, dec_bf);

    void* args[] = { (void*)&enc_bf, (void*)&dec_bf, (void*)&en_bf,
                     (void*)&w_c, (void*)&v, (void*)&mask,
                     (void*)&stats, (void*)&pctx, (void*)&out };
    hipLaunchCooperativeKernel((const void*)k_scan, dim3(256), dim3(1024),
                               args, 0, stream);
}

// Round 7
// 810.613 us; speedup vs baseline: 5.2663x; 1.1045x over previous
//
#include <hip/hip_runtime.h>
#include <float.h>

// Problem constants
#define B   32
#define TE  1024
#define TD  64
#define DE  512
#define DD  512
#define U   512
#define K   512   // == DE == DD
#define NB  8     // blocks per batch (256-block coop launch: proven geometry)
#define RPB 128   // t-rows per block

#if __has_builtin(__builtin_amdgcn_exp2f)
#define EXP2F __builtin_amdgcn_exp2f
#else
#define EXP2F exp2f
#endif
#if __has_builtin(__builtin_amdgcn_rcpf)
#define RCPF __builtin_amdgcn_rcpf
#else
#define RCPF(x) (1.0f / (x))
#endif

#define SENTINEL -1e30f

typedef __attribute__((ext_vector_type(8))) short bf16x8;  // 8 bf16 = 4 VGPRs
typedef __attribute__((ext_vector_type(4))) float f32x4;

__device__ __forceinline__ float tanh_fast(float x) {
    float e = EXP2F(x * 2.8853900817779268f);   // e^{2x}
    return 1.0f - 2.0f * RCPF(e + 1.0f);        // saturates correctly at +-inf
}

__device__ __forceinline__ float wave_reduce_sum(float v) {
    #pragma unroll
    for (int o = 32; o; o >>= 1) v += __shfl_xor(v, o, 64);
    return v;
}

// f32 -> bf16 RNE
__device__ __forceinline__ unsigned short f2bf(float f) {
    unsigned u = __float_as_uint(f);
    unsigned r = (u + 0x7fffu + ((u >> 16) & 1u)) >> 16;
    return (unsigned short)r;
}
__device__ __forceinline__ float bflo(unsigned x) { return __uint_as_float(x << 16); }
__device__ __forceinline__ float bfhi(unsigned x) { return __uint_as_float(x & 0xffff0000u); }
__device__ __forceinline__ void unpack8(uint4 q, float* f) {
    f[0] = bflo(q.x); f[1] = bfhi(q.x); f[2] = bflo(q.y); f[3] = bfhi(q.y);
    f[4] = bflo(q.z); f[5] = bfhi(q.z); f[6] = bflo(q.w); f[7] = bfhi(q.w);
}

// relaxed agent-scope (IC-level) accessors: per-instruction cache bypass,
// no wbl2/inv cache maintenance.
__device__ __forceinline__ float ld_agent(const float* p) {
    return __hip_atomic_load(p, __ATOMIC_RELAXED, __HIP_MEMORY_SCOPE_AGENT);
}
__device__ __forceinline__ void st_agent(float* p, float v) {
    __hip_atomic_store(p, v, __ATOMIC_RELAXED, __HIP_MEMORY_SCOPE_AGENT);
}
__device__ __forceinline__ unsigned long long ld_agent64(const unsigned long long* p) {
    return __hip_atomic_load(p, __ATOMIC_RELAXED, __HIP_MEMORY_SCOPE_AGENT);
}
__device__ __forceinline__ void st_agent64(unsigned long long* p, unsigned long long v) {
    __hip_atomic_store(p, v, __ATOMIC_RELAXED, __HIP_MEMORY_SCOPE_AGENT);
}

// ---------------------------------------------------------------------------
// init: stats tags = 0 (2*B*NB = 512 u64)
__global__ __launch_bounds__(256) void k_init(unsigned long long* __restrict__ stats) {
    int i = blockIdx.x * 256 + threadIdx.x;   // grid 2*256 = 512
    stats[i] = 0ull;
}

// en_seq f32 -> bf16
__global__ __launch_bounds__(256) void k_cast(const float4* __restrict__ in,
                                              ushort4* __restrict__ outp) {
    size_t i = (size_t)blockIdx.x * 256 + threadIdx.x;
    float4 f = in[i];
    ushort4 r;
    r.x = f2bf(f.x); r.y = f2bf(f.y); r.z = f2bf(f.z); r.w = f2bf(f.w);
    outp[i] = r;
}

// W[512,512] f32 -> Wt[n][k] bf16 (transpose + cast). 64x64 tile, 64 blocks.
__global__ __launch_bounds__(256) void k_transp(const float* __restrict__ W,
                                                unsigned short* __restrict__ Wt) {
    __shared__ float t[64][65];
    const int bx = blockIdx.x & 7, by = blockIdx.x >> 3;
    const int lx = threadIdx.x & 63, ly = threadIdx.x >> 6;
    #pragma unroll
    for (int i = 0; i < 64; i += 4)
        t[ly + i][lx] = W[(size_t)(by * 64 + ly + i) * 512 + bx * 64 + lx];
    __syncthreads();
    #pragma unroll
    for (int i = 0; i < 64; i += 4)
        Wt[(size_t)(bx * 64 + ly + i) * 512 + by * 64 + lx] = f2bf(t[lx][ly + i]);
}

// de_seq passthrough into out[:, :, 0:DD]
__global__ __launch_bounds__(256) void k_pass(const float4* __restrict__ de,
                                              float4* __restrict__ outp) {
    size_t i = (size_t)blockIdx.x * 256 + threadIdx.x;  // 262144 float4
    size_t r = i >> 7, c = i & 127;
    outp[r * 256 + c] = de[i];
}

// ---------------------------------------------------------------------------
// MFMA GEMM: C_bf16[M,512] = A_bf16[M,512] @ Wt_bf16[n][k]^T.
// 128x128 block tile, 4 waves a 64x64, frags direct from global.
// Layouts (m89/m91-verified): A[m=lane&15][k=quad*8+j], B[k=quad*8+j][n=lane&15],
// D col=lane&15, row=quad*4+reg.
__global__ __launch_bounds__(256) void k_mfma(const unsigned short* __restrict__ A,
                                              const unsigned short* __restrict__ Bt,
                                              unsigned short* __restrict__ C) {
    const int tid = threadIdx.x;
    const int w = tid >> 6, lane = tid & 63;
    const int quad = lane >> 4, l16 = lane & 15;
    const int m0 = blockIdx.y * 128 + (w >> 1) * 64;
    const int n0 = blockIdx.x * 128 + (w & 1) * 64;

    const short* Ab = (const short*)A  + (size_t)(m0 + l16) * K + quad * 8;
    const short* Bb = (const short*)Bt + (size_t)(n0 + l16) * K + quad * 8;

    f32x4 acc[4][4] = {};
    for (int ks = 0; ks < K; ks += 32) {
        bf16x8 af[4], bg[4];
        #pragma unroll
        for (int i = 0; i < 4; i++)
            af[i] = *(const bf16x8*)(Ab + (size_t)i * 16 * K + ks);
        #pragma unroll
        for (int j = 0; j < 4; j++)
            bg[j] = *(const bf16x8*)(Bb + (size_t)j * 16 * K + ks);
        #pragma unroll
        for (int i = 0; i < 4; i++)
            #pragma unroll
            for (int j = 0; j < 4; j++)
                acc[i][j] = __builtin_amdgcn_mfma_f32_16x16x32_bf16(
                    af[i], bg[j], acc[i][j], 0, 0, 0);
    }
    #pragma unroll
    for (int i = 0; i < 4; i++)
        #pragma unroll
        for (int j = 0; j < 4; j++)
            #pragma unroll
            for (int r = 0; r < 4; r++) {
                int m = m0 + i * 16 + quad * 4 + r;
                int n = n0 + j * 16 + l16;
                C[(size_t)m * U + n] = f2bf(acc[i][j][r]);
            }
}

// ---------------------------------------------------------------------------
// f32 vector GEMM (kept for the small dec GEMM, M=2048):
// C_bf16[M,512] = A[M,512] @ W[512,512].  64x64 tile, BK=16, 256 thr, 4x4/thr
__global__ __launch_bounds__(256) void k_gemm_bf(const float* __restrict__ A,
                                                 const float* __restrict__ W,
                                                 unsigned short* __restrict__ C) {
    __shared__ __align__(16) float As[16][68];
    __shared__ __align__(16) float Bs[16][64];
    const int tid = threadIdx.x;
    const int tx = tid & 15;
    const int ty = tid >> 4;
    const int m0 = blockIdx.y * 64;
    const int n0 = blockIdx.x * 64;

    float acc[4][4];
    #pragma unroll
    for (int i = 0; i < 4; i++)
        #pragma unroll
        for (int j = 0; j < 4; j++) acc[i][j] = 0.f;

    for (int k0 = 0; k0 < K; k0 += 16) {
        #pragma unroll
        for (int i = 0; i < 4; i++) {
            int id = i * 256 + tid;
            int m = id >> 4, kk = id & 15;
            As[kk][m] = A[(size_t)(m0 + m) * K + k0 + kk];
        }
        #pragma unroll
        for (int i = 0; i < 4; i++) {
            int id = i * 256 + tid;
            int n = id & 63, kk = id >> 6;
            Bs[kk][n] = W[(size_t)(k0 + kk) * U + n0 + n];
        }
        __syncthreads();
        #pragma unroll
        for (int kk = 0; kk < 16; kk++) {
            float4 a4 = *(const float4*)&As[kk][ty * 4];
            float4 b4 = *(const float4*)&Bs[kk][tx * 4];
            float a[4] = {a4.x, a4.y, a4.z, a4.w};
            float b[4] = {b4.x, b4.y, b4.z, b4.w};
            #pragma unroll
            for (int i = 0; i < 4; i++)
                #pragma unroll
                for (int j = 0; j < 4; j++) acc[i][j] += a[i] * b[j];
        }
        __syncthreads();
    }
    #pragma unroll
    for (int i = 0; i < 4; i++) {
        ushort4 r;
        r.x = f2bf(acc[i][0]); r.y = f2bf(acc[i][1]);
        r.z = f2bf(acc[i][2]); r.w = f2bf(acc[i][3]);
        *(ushort4*)&C[(size_t)(m0 + ty * 4 + i) * U + n0 + tx * 4] = r;
    }
}

// ---------------------------------------------------------------------------
// Persistent scan: 256 blocks x 1024 threads, cooperative (proven geometry).
// block -> (b = blk&31, g = blk>>5). Block owns t-rows [g*128, g*128+128);
// its enc slice lives in LDS (128 KB, loaded once).
// No max-subtraction softmax (|mu| <= sum|v| ~ 18): each block publishes ONE
// u64 (sum_g:f32 | tag:u32=s+1) per step — sync + reduction in one IC RTT.
// pctx(s-1) visibility: pre-publish __syncthreads drains vmcnt(0)
// (compiler-emitted), so tag==s+1 from all 8 blocks implies IC-visibility.
__global__ __launch_bounds__(1024, 4) void k_scan(
        const unsigned short* __restrict__ enc_bf,
        const unsigned short* __restrict__ dec_bf,
        const unsigned short* __restrict__ en_bf,
        const float* __restrict__ w_c,
        const float* __restrict__ v,
        const int* __restrict__ mask,
        unsigned long long* __restrict__ stats,  // [2][B][NB]
        float* __restrict__ pctx,                // [2][B][NB][512]
        float* __restrict__ out)
{
    const int blk = blockIdx.x;
    const int b = blk & 31, g = blk >> 5;    // XCD-local batch grouping
    const int tid = threadIdx.x;
    const int w = tid >> 6, lane = tid & 63;
    const int u = lane * 8;
    const float L2E = 1.4426950408889634f;

    __shared__ __align__(16) unsigned short s_enc[RPB * U];  // 128 KiB
    __shared__ float  s_mu[RPB];
    __shared__ float  s_alpha[RPB];
    __shared__ float  s_cov[RPB];
    __shared__ int    s_active[RPB];
    __shared__ float  s_wsum[16];
    __shared__ float  s_cred[NB][64];        // 2 KiB
    __shared__ float2 s_p6[4][256];          // 8 KiB
    __shared__ float  s_inv;
    __shared__ int    s_nact;

    const int* maskb = mask + b * TE;
    const unsigned short* encb = enc_bf + ((size_t)b * TE + g * RPB) * U;
    float* alphas = out + (size_t)B * TD * (DD + DE);
    float* covl   = alphas + (size_t)B * TD * TE;

    // lane-resident w_c / v fragments
    float wc[8], vv[8];
    {
        float4 a0 = *(const float4*)&w_c[u];
        float4 a1 = *(const float4*)&w_c[u + 4];
        wc[0]=a0.x; wc[1]=a0.y; wc[2]=a0.z; wc[3]=a0.w;
        wc[4]=a1.x; wc[5]=a1.y; wc[6]=a1.z; wc[7]=a1.w;
        float4 b0 = *(const float4*)&v[u];
        float4 b1 = *(const float4*)&v[u + 4];
        vv[0]=b0.x; vv[1]=b0.y; vv[2]=b0.z; vv[3]=b0.w;
        vv[4]=b1.x; vv[5]=b1.y; vv[6]=b1.z; vv[7]=b1.w;
    }

    // stage own enc slice into LDS: 131072 B = 8192 uint4, 8 iters
    {
        const uint4* src = (const uint4*)encb;
        uint4* dst = (uint4*)s_enc;
        #pragma unroll
        for (int i = 0; i < 8; i++) dst[i * 1024 + tid] = src[i * 1024 + tid];
    }

    // active-row compaction (waves 0-1, 128 rows), mu/cov init
    {
        int act = 0;
        if (tid < RPB) act = (maskb[g * RPB + tid] != 0);
        unsigned long long bal = __ballot(act);
        int pre = __popcll(bal & ((1ull << lane) - 1));
        __shared__ int s_c2[2];
        if (w < 2 && lane == 0) s_c2[w] = __popcll(bal);
        if (tid < RPB) { s_mu[tid] = SENTINEL; s_cov[tid] = 0.f; }
        __syncthreads();
        if (act) {
            int base = (w == 1) ? s_c2[0] : 0;
            s_active[base + pre] = tid;
        }
        if (tid == 0) s_nact = s_c2[0] + s_c2[1];
        __syncthreads();
    }
    const int n_act = s_nact;

    for (int s = 0; s < TD; s++) {
        // ---- dec fragment for (b,s)
        float df[8];
        {
            uint4 q = *(const uint4*)(dec_bf + (((size_t)b * TD + s) * U + u));
            unpack8(q, df);
        }

        // ---- phase 1: mu over own active rows (enc from LDS) + local expsum
        float local_esum = 0.f;
        for (int i = w; i < n_act; i += 16) {
            int r = s_active[i];
            float cov = s_cov[r];
            uint4 q = *(const uint4*)(s_enc + (size_t)r * U + u);
            float e[8]; unpack8(q, e);
            float acc = 0.f;
            #pragma unroll
            for (int j = 0; j < 8; j++)
                acc += vv[j] * tanh_fast(fmaf(cov, wc[j], e[j] + df[j]));
            acc = wave_reduce_sum(acc);
            if (lane == 0) s_mu[r] = acc;
            local_esum += EXP2F(acc * L2E);
        }
        if (lane == 0) s_wsum[w] = local_esum;

        __syncthreads();   // B1: drains pctx(s-1) agent-stores (vmcnt(0))

        // ---- publish (sum_g | tag s+1), poll all 8 tags (wave 0 only)
        if (w == 0) {
            float sg = (lane < 16) ? s_wsum[lane] : 0.f;
            sg = wave_reduce_sum(sg);
            unsigned long long* sl = stats + ((size_t)(s & 1) * B + b) * NB;
            if (lane == 0) {
                unsigned long long pv =
                    ((unsigned long long)__float_as_uint(sg) << 32) |
                    (unsigned)(s + 1);
                st_agent64(&sl[g], pv);
            }
            unsigned long long pv = 0;
            for (;;) {
                if (lane < NB) pv = ld_agent64(&sl[lane]);
                unsigned long long okm =
                    __ballot(lane < NB ? ((unsigned)pv == (unsigned)(s + 1)) : 1);
                if (~okm == 0ull) break;
                __builtin_amdgcn_s_sleep(1);
            }
            float tg = (lane < NB) ? __uint_as_float((unsigned)(pv >> 32)) : 0.f;
            tg = wave_reduce_sum(tg);
            if (lane == 0) s_inv = RCPF(tg);
        }
        __syncthreads();   // B2

        const float inv = s_inv;

        // ---- deferred ctx(s-1) partial loads (IC)  [threads 0..511]
        if (s > 0 && tid < 512) {
            int gg = tid >> 6, e = tid & 63;
            s_cred[gg][e] = ld_agent(
                &pctx[(((size_t)((s - 1) & 1) * B + b) * NB + gg) * 512 + g * 64 + e]);
        }
        // ---- own-row alpha/cov/outputs  [threads 512..639]
        if (tid >= 512 && tid < 512 + RPB) {
            int r = tid - 512;
            float a = EXP2F(s_mu[r] * L2E) * inv;   // masked -> exactly 0
            float cov = s_cov[r];
            size_t rowo = ((size_t)b * TD + s) * TE + g * RPB + r;
            alphas[rowo] = a;
            covl[rowo]   = fminf(cov, a);
            s_alpha[r] = a;
            s_cov[r] = cov + a;
        }
        __syncthreads();   // B3

        // ---- ctx(s-1) final reduce + store  [threads 0..63]
        if (s > 0 && tid < 64) {
            float ts = 0.f;
            #pragma unroll
            for (int gg = 0; gg < NB; gg++) ts += s_cred[gg][tid];
            out[((size_t)b * TD + (s - 1)) * (DD + DE) + DD + g * 64 + tid] = ts;
        }

        // ---- phase 6: partial ctx over ACTIVE own rows only (en from L2)
        {
            const int e2 = tid & 255, q = tid >> 8;   // 256 e-pairs x 4 quarters
            const int na4 = (n_act + 3) >> 2;
            const int i0 = q * na4;
            const int i1 = (i0 + na4 < n_act) ? (i0 + na4) : n_act;
            const unsigned* ebase =
                (const unsigned*)(en_bf + ((size_t)b * TE + g * RPB) * DE);
            float a0 = 0.f, a1 = 0.f;
            for (int i = i0; i < i1; i++) {
                int r = s_active[i];              // wave-uniform broadcast
                float a = s_alpha[r];             // wave-uniform broadcast
                unsigned qq = ebase[(size_t)r * (DE / 2) + e2];
                a0 = fmaf(a, bflo(qq), a0);
                a1 = fmaf(a, bfhi(qq), a1);
            }
            s_p6[q][e2] = make_float2(a0, a1);
        }
        __syncthreads();   // B4
        if (tid < 256) {
            float2 p0 = s_p6[0][tid], p1 = s_p6[1][tid];
            float2 p2 = s_p6[2][tid], p3 = s_p6[3][tid];
            float* pw = pctx + (((size_t)(s & 1) * B + b) * NB + g) * 512;
            st_agent(&pw[2 * tid],     p0.x + p1.x + p2.x + p3.x);
            st_agent(&pw[2 * tid + 1], p0.y + p1.y + p2.y + p3.y);
        }
    }

    // ---- epilogue: one more tag round, then reduce pctx(TD-1)
    __syncthreads();       // drains pctx(TD-1) stores
    if (w == 0) {
        unsigned long long* sl = stats + ((size_t)(TD & 1) * B + b) * NB;
        if (lane == 0) st_agent64(&sl[g], (unsigned long long)(TD + 1));
        unsigned long long pv = 0;
        for (;;) {
            if (lane < NB) pv = ld_agent64(&sl[lane]);
            unsigned long long okm =
                __ballot(lane < NB ? ((unsigned)pv == (unsigned)(TD + 1)) : 1);
            if (~okm == 0ull) break;
            __builtin_amdgcn_s_sleep(1);
        }
    }
    __syncthreads();
    if (tid < 512) {
        int gg = tid >> 6, e = tid & 63;
        s_cred[gg][e] = ld_agent(
            &pctx[(((size_t)((TD - 1) & 1) * B + b) * NB + gg) * 512 + g * 64 + e]);
    }
    __syncthreads();
    if (tid < 64) {
        float ts = 0.f;
        #pragma unroll
        for (int gg = 0; gg < NB; gg++) ts += s_cred[gg][tid];
        out[((size_t)b * TD + (TD - 1)) * (DD + DE) + DD + g * 64 + tid] = ts;
    }
}

// ---------------------------------------------------------------------------
extern "C" void kernel_launch(void* const* d_in, const int* in_sizes, int n_in,
                              void* d_out, int out_size, void* d_ws, size_t ws_size,
                              hipStream_t stream) {
    const float* en_seq = (const float*)d_in[0];
    const float* de_seq = (const float*)d_in[1];
    const int*   mask   = (const int*)d_in[2];
    const float* W_h    = (const float*)d_in[3];
    const float* W_s    = (const float*)d_in[4];
    const float* w_c    = (const float*)d_in[5];
    const float* v      = (const float*)d_in[6];
    float* out = (float*)d_out;

    // workspace layout (~67.6 MiB)
    unsigned short* enc_bf = (unsigned short*)d_ws;        // B*TE*U  bf16 = 32 MiB
    unsigned short* en_bf  = enc_bf + (size_t)B * TE * U;  // B*TE*DE bf16 = 32 MiB
    unsigned short* dec_bf = en_bf  + (size_t)B * TE * DE; // B*TD*U  bf16 = 2 MiB
    unsigned short* Wh_t   = dec_bf + (size_t)B * TD * U;  // 512*512 bf16 = 0.5 MiB
    float* pctx = (float*)(Wh_t + (size_t)K * U);          // 2*B*NB*512 f32 = 1 MiB
    unsigned long long* stats =
        (unsigned long long*)(pctx + (size_t)2 * B * NB * 512);  // 512 u64

    k_init<<<2, 256, 0, stream>>>(stats);
    k_cast<<<16384, 256, 0, stream>>>((const float4*)en_seq, (ushort4*)en_bf);
    k_transp<<<64, 256, 0, stream>>>(W_h, Wh_t);
    k_pass<<<1024, 256, 0, stream>>>((const float4*)de_seq, (float4*)out);
    k_mfma<<<dim3(U / 128, (B * TE) / 128), 256, 0, stream>>>(en_bf, Wh_t, enc_bf);
    k_gemm_bf<<<dim3(U / 64, (B * TD) / 64), 256, 0, stream>>>(de_seq, W_s, dec_bf);

    void* args[] = { (void*)&enc_bf, (void*)&dec_bf, (void*)&en_bf,
                     (void*)&w_c, (void*)&v, (void*)&mask,
                     (void*)&stats, (void*)&pctx, (void*)&out };
    hipLaunchCooperativeKernel((const void*)k_scan, dim3(256), dim3(1024),
                               args, 0, stream);
}

// Round 8
// 762.243 us; speedup vs baseline: 5.6004x; 1.0635x over previous
//
#include <hip/hip_runtime.h>
#include <float.h>

// Problem constants
#define B   32
#define TE  1024
#define TD  64
#define DE  512
#define DD  512
#define U   512
#define K   512   // == DE == DD
#define NB  8     // blocks per batch (256-block coop launch: proven geometry)
#define RPB 128   // t-rows per block

#if __has_builtin(__builtin_amdgcn_exp2f)
#define EXP2F __builtin_amdgcn_exp2f
#else
#define EXP2F exp2f
#endif
#if __has_builtin(__builtin_amdgcn_rcpf)
#define RCPF __builtin_amdgcn_rcpf
#else
#define RCPF(x) (1.0f / (x))
#endif

#define SENTINEL -1e30f

typedef __attribute__((ext_vector_type(8))) short bf16x8;  // 8 bf16 = 4 VGPRs
typedef __attribute__((ext_vector_type(4))) float f32x4;

__device__ __forceinline__ float tanh_fast(float x) {
    float e = EXP2F(x * 2.8853900817779268f);   // e^{2x}
    return 1.0f - 2.0f * RCPF(e + 1.0f);        // saturates correctly at +-inf
}

__device__ __forceinline__ float wave_reduce_sum(float v) {
    #pragma unroll
    for (int o = 32; o; o >>= 1) v += __shfl_xor(v, o, 64);
    return v;
}

// f32 -> bf16 RNE
__device__ __forceinline__ unsigned short f2bf(float f) {
    unsigned u = __float_as_uint(f);
    unsigned r = (u + 0x7fffu + ((u >> 16) & 1u)) >> 16;
    return (unsigned short)r;
}
__device__ __forceinline__ float bflo(unsigned x) { return __uint_as_float(x << 16); }
__device__ __forceinline__ float bfhi(unsigned x) { return __uint_as_float(x & 0xffff0000u); }
__device__ __forceinline__ void unpack8(uint4 q, float* f) {
    f[0] = bflo(q.x); f[1] = bfhi(q.x); f[2] = bflo(q.y); f[3] = bfhi(q.y);
    f[4] = bflo(q.z); f[5] = bfhi(q.z); f[6] = bflo(q.w); f[7] = bfhi(q.w);
}

// relaxed agent-scope (IC-level) accessors: per-instruction cache bypass,
// no wbl2/inv cache maintenance.
__device__ __forceinline__ float ld_agent(const float* p) {
    return __hip_atomic_load(p, __ATOMIC_RELAXED, __HIP_MEMORY_SCOPE_AGENT);
}
__device__ __forceinline__ void st_agent(float* p, float v) {
    __hip_atomic_store(p, v, __ATOMIC_RELAXED, __HIP_MEMORY_SCOPE_AGENT);
}
__device__ __forceinline__ unsigned long long ld_agent64(const unsigned long long* p) {
    return __hip_atomic_load(p, __ATOMIC_RELAXED, __HIP_MEMORY_SCOPE_AGENT);
}
__device__ __forceinline__ void st_agent64(unsigned long long* p, unsigned long long v) {
    __hip_atomic_store(p, v, __ATOMIC_RELAXED, __HIP_MEMORY_SCOPE_AGENT);
}

// ---------------------------------------------------------------------------
// Fused prep: en cast [0,16384) | de cast [16384,17408) | pass [17408,18432)
// | W transposes [18432,18560) | stats init [18560,18562). One launch.
__global__ __launch_bounds__(256) void k_prep(
        const float4* __restrict__ en_seq, ushort4* __restrict__ en_bf,
        const float4* __restrict__ de_seq, ushort4* __restrict__ de_bf,
        float4* __restrict__ outp,
        const float* __restrict__ W_h, unsigned short* __restrict__ Wh_t,
        const float* __restrict__ W_s, unsigned short* __restrict__ Ws_t,
        unsigned long long* __restrict__ stats)
{
    __shared__ float t[64][65];
    const int blk = blockIdx.x;
    const int tid = threadIdx.x;
    if (blk < 16384) {                       // en_seq f32 -> bf16
        size_t i = (size_t)blk * 256 + tid;
        float4 f = en_seq[i];
        ushort4 r; r.x = f2bf(f.x); r.y = f2bf(f.y); r.z = f2bf(f.z); r.w = f2bf(f.w);
        en_bf[i] = r;
    } else if (blk < 17408) {                // de_seq f32 -> bf16
        size_t i = (size_t)(blk - 16384) * 256 + tid;
        float4 f = de_seq[i];
        ushort4 r; r.x = f2bf(f.x); r.y = f2bf(f.y); r.z = f2bf(f.z); r.w = f2bf(f.w);
        de_bf[i] = r;
    } else if (blk < 18432) {                // de_seq passthrough -> out[:,:,0:DD]
        size_t i = (size_t)(blk - 17408) * 256 + tid;
        size_t r = i >> 7, c = i & 127;
        outp[r * 256 + c] = de_seq[i];
    } else if (blk < 18560) {                // W transpose+cast: Wt[n][k]=W[k][n]
        int id = blk - 18432;
        const float* W = (id < 64) ? W_h : W_s;
        unsigned short* Wt = (id < 64) ? Wh_t : Ws_t;
        int bid = id & 63;
        const int bx = bid & 7, by = bid >> 3;
        const int lx = tid & 63, ly = tid >> 6;
        #pragma unroll
        for (int i = 0; i < 64; i += 4)
            t[ly + i][lx] = W[(size_t)(by * 64 + ly + i) * 512 + bx * 64 + lx];
        __syncthreads();
        #pragma unroll
        for (int i = 0; i < 64; i += 4)
            Wt[(size_t)(bx * 64 + ly + i) * 512 + by * 64 + lx] = f2bf(t[lx][ly + i]);
    } else {                                 // stats init (512 u64)
        int i = (blk - 18560) * 256 + tid;
        stats[i] = 0ull;
    }
}

// ---------------------------------------------------------------------------
// Unified MFMA GEMM: C_bf16[M,512] = A_bf16[M,512] @ Wt_bf16[n][k]^T.
// grid (4, 272): y<256 -> enc (M=32768), y>=256 -> dec (M=2048).
// 128x128 block tile, 4 waves a 64x64, frags direct from global.
// Layouts (m89/m91-verified): A[m=lane&15][k=quad*8+j], B[k=quad*8+j][n=lane&15],
// D col=lane&15, row=quad*4+reg.
__global__ __launch_bounds__(256) void k_mfma(
        const unsigned short* __restrict__ Ae, const unsigned short* __restrict__ Be,
        unsigned short* __restrict__ Ce,
        const unsigned short* __restrict__ Ad, const unsigned short* __restrict__ Bd,
        unsigned short* __restrict__ Cd)
{
    const int tid = threadIdx.x;
    const int w = tid >> 6, lane = tid & 63;
    const int quad = lane >> 4, l16 = lane & 15;
    const short* A; const short* Bt; unsigned short* C; int mb;
    if (blockIdx.y < 256) {
        A = (const short*)Ae; Bt = (const short*)Be; C = Ce; mb = blockIdx.y * 128;
    } else {
        A = (const short*)Ad; Bt = (const short*)Bd; C = Cd; mb = (blockIdx.y - 256) * 128;
    }
    const int m0 = mb + (w >> 1) * 64;
    const int n0 = blockIdx.x * 128 + (w & 1) * 64;

    const short* Ab = A  + (size_t)(m0 + l16) * K + quad * 8;
    const short* Bb = Bt + (size_t)(n0 + l16) * K + quad * 8;

    f32x4 acc[4][4] = {};
    for (int ks = 0; ks < K; ks += 32) {
        bf16x8 af[4], bg[4];
        #pragma unroll
        for (int i = 0; i < 4; i++)
            af[i] = *(const bf16x8*)(Ab + (size_t)i * 16 * K + ks);
        #pragma unroll
        for (int j = 0; j < 4; j++)
            bg[j] = *(const bf16x8*)(Bb + (size_t)j * 16 * K + ks);
        #pragma unroll
        for (int i = 0; i < 4; i++)
            #pragma unroll
            for (int j = 0; j < 4; j++)
                acc[i][j] = __builtin_amdgcn_mfma_f32_16x16x32_bf16(
                    af[i], bg[j], acc[i][j], 0, 0, 0);
    }
    #pragma unroll
    for (int i = 0; i < 4; i++)
        #pragma unroll
        for (int j = 0; j < 4; j++)
            #pragma unroll
            for (int r = 0; r < 4; r++) {
                int m = m0 + i * 16 + quad * 4 + r;
                int n = n0 + j * 16 + l16;
                C[(size_t)m * U + n] = f2bf(acc[i][j][r]);
            }
}

// ---------------------------------------------------------------------------
// Persistent scan: 256 blocks x 1024 threads, cooperative (proven geometry).
// block -> (b = blk&31, g = blk>>5). Block owns t-rows [g*128, g*128+128);
// its enc slice lives in LDS (128 KB, loaded once).
// TWO barriers per step (was 4 + serialized poll):
//   phase1 -> B1 -> publish(w0/l0) + PER-WAVE poll (each wave computes inv
//   itself) -> phase5 (waves 0-1) & cred loads (all waves) -> B3 ->
//   ctx(s-1) reduce+store & phase6 (partials straight to pctx, no LDS reduce)
// pctx is [2][B][NB*4][512]: each block stores 4 row-quarter partials; the
// reduce side sums 32 slots. Visibility: B1 drains pctx(s-1) agent-stores
// (compiler-emitted vmcnt(0) before s_barrier); tag==s+1 from all 8 blocks
// implies all pctx(s-1) stores are IC-visible.
__global__ __launch_bounds__(1024, 4) void k_scan(
        const unsigned short* __restrict__ enc_bf,
        const unsigned short* __restrict__ dec_bf,
        const unsigned short* __restrict__ en_bf,
        const float* __restrict__ w_c,
        const float* __restrict__ v,
        const int* __restrict__ mask,
        unsigned long long* __restrict__ stats,  // [2][B][NB]
        float* __restrict__ pctx,                // [2][B][NB*4][512]
        float* __restrict__ out)
{
    const int blk = blockIdx.x;
    const int b = blk & 31, g = blk >> 5;    // XCD-local batch grouping
    const int tid = threadIdx.x;
    const int w = tid >> 6, lane = tid & 63;
    const int u = lane * 8;
    const float L2E = 1.4426950408889634f;

    __shared__ __align__(16) unsigned short s_enc[RPB * U];  // 128 KiB
    __shared__ float  s_mu[RPB];
    __shared__ float  s_alpha[RPB];
    __shared__ float  s_cov[RPB];
    __shared__ int    s_active[RPB];
    __shared__ float  s_wsum[16];
    __shared__ float  s_cred[4 * NB][64];    // 8 KiB
    __shared__ int    s_nact;

    const int* maskb = mask + b * TE;
    const unsigned short* encb = enc_bf + ((size_t)b * TE + g * RPB) * U;
    float* alphas = out + (size_t)B * TD * (DD + DE);
    float* covl   = alphas + (size_t)B * TD * TE;

    // lane-resident w_c / v fragments
    float wc[8], vv[8];
    {
        float4 a0 = *(const float4*)&w_c[u];
        float4 a1 = *(const float4*)&w_c[u + 4];
        wc[0]=a0.x; wc[1]=a0.y; wc[2]=a0.z; wc[3]=a0.w;
        wc[4]=a1.x; wc[5]=a1.y; wc[6]=a1.z; wc[7]=a1.w;
        float4 b0 = *(const float4*)&v[u];
        float4 b1 = *(const float4*)&v[u + 4];
        vv[0]=b0.x; vv[1]=b0.y; vv[2]=b0.z; vv[3]=b0.w;
        vv[4]=b1.x; vv[5]=b1.y; vv[6]=b1.z; vv[7]=b1.w;
    }

    // stage own enc slice into LDS: 131072 B = 8192 uint4, 8 iters
    {
        const uint4* src = (const uint4*)encb;
        uint4* dst = (uint4*)s_enc;
        #pragma unroll
        for (int i = 0; i < 8; i++) dst[i * 1024 + tid] = src[i * 1024 + tid];
    }

    // active-row compaction (waves 0-1, 128 rows), mu/cov init
    {
        int act = 0;
        if (tid < RPB) act = (maskb[g * RPB + tid] != 0);
        unsigned long long bal = __ballot(act);
        int pre = __popcll(bal & ((1ull << lane) - 1));
        __shared__ int s_c2[2];
        if (w < 2 && lane == 0) s_c2[w] = __popcll(bal);
        if (tid < RPB) { s_mu[tid] = SENTINEL; s_cov[tid] = 0.f; }
        __syncthreads();
        if (act) {
            int base = (w == 1) ? s_c2[0] : 0;
            s_active[base + pre] = tid;
        }
        if (tid == 0) s_nact = s_c2[0] + s_c2[1];
        __syncthreads();
    }
    const int n_act = s_nact;

    for (int s = 0; s < TD; s++) {
        // ---- dec fragment for (b,s)
        float df[8];
        {
            uint4 q = *(const uint4*)(dec_bf + (((size_t)b * TD + s) * U + u));
            unpack8(q, df);
        }

        // ---- phase 1: mu over own active rows (enc from LDS) + local expsum
        float local_esum = 0.f;
        for (int i = w; i < n_act; i += 16) {
            int r = s_active[i];
            float cov = s_cov[r];
            uint4 q = *(const uint4*)(s_enc + (size_t)r * U + u);
            float e[8]; unpack8(q, e);
            float acc = 0.f;
            #pragma unroll
            for (int j = 0; j < 8; j++)
                acc += vv[j] * tanh_fast(fmaf(cov, wc[j], e[j] + df[j]));
            acc = wave_reduce_sum(acc);
            if (lane == 0) s_mu[r] = acc;
            local_esum += EXP2F(acc * L2E);
        }
        if (lane == 0) s_wsum[w] = local_esum;

        __syncthreads();   // B1: drains pctx(s-1) agent-stores (vmcnt(0))

        // ---- publish (sum_g | tag s+1): wave 0 lane 0 only
        unsigned long long* sl = stats + ((size_t)(s & 1) * B + b) * NB;
        {
            float x = (lane < 16) ? s_wsum[lane] : 0.f;
            float sg = wave_reduce_sum(x);
            if (w == 0 && lane == 0) {
                unsigned long long pv =
                    ((unsigned long long)__float_as_uint(sg) << 32) |
                    (unsigned)(s + 1);
                st_agent64(&sl[g], pv);
            }
        }
        // ---- per-wave poll of all 8 tags -> batch expsum -> inv
        float inv;
        {
            unsigned long long pv = 0;
            for (;;) {
                if (lane < NB) pv = ld_agent64(&sl[lane]);
                unsigned long long okm =
                    __ballot(lane < NB ? ((unsigned)pv == (unsigned)(s + 1)) : 1);
                if (~okm == 0ull) break;
                __builtin_amdgcn_s_sleep(1);
            }
            float tg = (lane < NB) ? __uint_as_float((unsigned)(pv >> 32)) : 0.f;
            tg = wave_reduce_sum(tg);
            inv = RCPF(tg);
        }

        // ---- phase 5: own-row alpha/cov/outputs  [waves 0-1]
        if (tid < RPB) {
            float a = EXP2F(s_mu[tid] * L2E) * inv;   // masked -> exactly 0
            float cov = s_cov[tid];
            size_t rowo = ((size_t)b * TD + s) * TE + g * RPB + tid;
            alphas[rowo] = a;
            covl[rowo]   = fminf(cov, a);
            s_alpha[tid] = a;
            s_cov[tid] = cov + a;
        }
        // ---- cred loads for ctx(s-1): all threads, 2 floats each
        if (s > 0) {
            int slot = tid >> 5;             // 0..31
            int e = (tid & 31) * 2;          // 0..62
            const float* pp = pctx +
                (((size_t)((s - 1) & 1) * B + b) * (NB * 4) + slot) * 512 + g * 64;
            s_cred[slot][e]     = ld_agent(&pp[e]);
            s_cred[slot][e + 1] = ld_agent(&pp[e + 1]);
        }
        __syncthreads();   // B3

        // ---- ctx(s-1) final reduce + store  [threads 0..63]
        if (s > 0 && tid < 64) {
            float ts = 0.f;
            #pragma unroll
            for (int sl2 = 0; sl2 < 4 * NB; sl2++) ts += s_cred[sl2][tid];
            out[((size_t)b * TD + (s - 1)) * (DD + DE) + DD + g * 64 + tid] = ts;
        }

        // ---- phase 6: partial ctx, own 128 rows x 512 e, branchless unrolled;
        //      per-quarter partials straight to pctx (no LDS reduce, no B4)
        {
            const int e2 = tid & 255, q = tid >> 8;   // 256 e-pairs x 4 quarters
            const unsigned* ep = (const unsigned*)
                (en_bf + ((size_t)b * TE + g * RPB + q * 32) * DE) + e2;
            float a0 = 0.f, a1 = 0.f;
            #pragma unroll
            for (int r = 0; r < 32; r++) {
                float a = s_alpha[q * 32 + r];
                unsigned qq = ep[(size_t)r * (DE / 2)];
                a0 = fmaf(a, bflo(qq), a0);           // masked: a==0 exact
                a1 = fmaf(a, bfhi(qq), a1);
            }
            float* pw = pctx +
                (((size_t)(s & 1) * B + b) * (NB * 4) + (g * 4 + q)) * 512;
            st_agent(&pw[2 * e2],     a0);
            st_agent(&pw[2 * e2 + 1], a1);
        }
    }

    // ---- epilogue: one more tag round, then reduce pctx(TD-1)
    __syncthreads();       // drains pctx(TD-1) stores
    {
        unsigned long long* sl = stats + ((size_t)(TD & 1) * B + b) * NB;
        if (w == 0 && lane == 0)
            st_agent64(&sl[g], (unsigned long long)(unsigned)(TD + 1));
        unsigned long long pv = 0;
        for (;;) {
            if (lane < NB) pv = ld_agent64(&sl[lane]);
            unsigned long long okm =
                __ballot(lane < NB ? ((unsigned)pv == (unsigned)(TD + 1)) : 1);
            if (~okm == 0ull) break;
            __builtin_amdgcn_s_sleep(1);
        }
    }
    {
        int slot = tid >> 5;
        int e = (tid & 31) * 2;
        const float* pp = pctx +
            (((size_t)((TD - 1) & 1) * B + b) * (NB * 4) + slot) * 512 + g * 64;
        s_cred[slot][e]     = ld_agent(&pp[e]);
        s_cred[slot][e + 1] = ld_agent(&pp[e + 1]);
    }
    __syncthreads();
    if (tid < 64) {
        float ts = 0.f;
        #pragma unroll
        for (int sl2 = 0; sl2 < 4 * NB; sl2++) ts += s_cred[sl2][tid];
        out[((size_t)b * TD + (TD - 1)) * (DD + DE) + DD + g * 64 + tid] = ts;
    }
}

// ---------------------------------------------------------------------------
extern "C" void kernel_launch(void* const* d_in, const int* in_sizes, int n_in,
                              void* d_out, int out_size, void* d_ws, size_t ws_size,
                              hipStream_t stream) {
    const float* en_seq = (const float*)d_in[0];
    const float* de_seq = (const float*)d_in[1];
    const int*   mask   = (const int*)d_in[2];
    const float* W_h    = (const float*)d_in[3];
    const float* W_s    = (const float*)d_in[4];
    const float* w_c    = (const float*)d_in[5];
    const float* v      = (const float*)d_in[6];
    float* out = (float*)d_out;

    // workspace layout (~70.5 MiB). de_bf/Ws_t ALIAS pctx (lifetimes disjoint:
    // both are dead before k_scan first writes pctx).
    unsigned short* enc_bf = (unsigned short*)d_ws;        // B*TE*U  bf16 = 32 MiB
    unsigned short* en_bf  = enc_bf + (size_t)B * TE * U;  // B*TE*DE bf16 = 32 MiB
    unsigned short* dec_bf = en_bf  + (size_t)B * TE * DE; // B*TD*U  bf16 = 2 MiB
    unsigned short* Wh_t   = dec_bf + (size_t)B * TD * U;  // 512*512 bf16 = 0.5 MiB
    float* pctx = (float*)(Wh_t + (size_t)K * U);          // 2*B*32*512 f32 = 4 MiB
    unsigned short* de_bf  = (unsigned short*)pctx;        // B*TD*DD bf16 = 2 MiB (alias)
    unsigned short* Ws_t   = de_bf + (size_t)B * TD * DD;  // 0.5 MiB (alias)
    unsigned long long* stats =
        (unsigned long long*)(pctx + (size_t)2 * B * 32 * 512);  // 512 u64

    k_prep<<<18562, 256, 0, stream>>>((const float4*)en_seq, (ushort4*)en_bf,
                                      (const float4*)de_seq, (ushort4*)de_bf,
                                      (float4*)out, W_h, Wh_t, W_s, Ws_t, stats);
    k_mfma<<<dim3(4, 272), 256, 0, stream>>>(en_bf, Wh_t, enc_bf,
                                             de_bf, Ws_t, dec_bf);

    void* args[] = { (void*)&enc_bf, (void*)&dec_bf, (void*)&en_bf,
                     (void*)&w_c, (void*)&v, (void*)&mask,
                     (void*)&stats, (void*)&pctx, (void*)&out };
    hipLaunchCooperativeKernel((const void*)k_scan, dim3(256), dim3(1024),
                               args, 0, stream);
}